// Round 1
// baseline (336.507 us; speedup 1.0000x reference)
//
#include <hip/hip_runtime.h>
#include <stdint.h>

typedef unsigned short u16;
typedef __bf16 bf16x8 __attribute__((ext_vector_type(8)));
typedef float  f32x4  __attribute__((ext_vector_type(4)));

#define B_  2
#define T_  1024
#define C_  2048
#define H_  16
#define D_  128
#define NTENS 4194304   // elements in x and in each W (2*1024*2048 == 2048*2048)

__device__ __forceinline__ u16 f2bf(float f) {
    union { float f; uint32_t u; } v; v.f = f;
    uint32_t r = (v.u + 0x7FFFu + ((v.u >> 16) & 1u)) >> 16;
    return (u16)r;
}
__device__ __forceinline__ float bf2f(u16 h) {
    union { uint32_t u; float f; } v; v.u = ((uint32_t)h) << 16;
    return v.f;
}

// ---------------------------------------------------------------------------
// fp32 -> bf16 conversion: z selects {x, Wq, Wk, Wv, Wo}; dst is contiguous.
// ---------------------------------------------------------------------------
__global__ __launch_bounds__(256) void k_convert(
    const float* __restrict__ x, const float* __restrict__ wq,
    const float* __restrict__ wk, const float* __restrict__ wv,
    const float* __restrict__ wo, u16* __restrict__ dst)
{
    int z = blockIdx.z;
    const float* src = (z == 0) ? x : (z == 1) ? wq : (z == 2) ? wk : (z == 3) ? wv : wo;
    u16* d = dst + (size_t)z * NTENS;
    size_t i = ((size_t)blockIdx.x * 256 + threadIdx.x) * 4;
    float4 v = *(const float4*)(src + i);
    ushort4 o;
    o.x = f2bf(v.x); o.y = f2bf(v.y); o.z = f2bf(v.z); o.w = f2bf(v.w);
    *(ushort4*)(d + i) = o;
}

// ---------------------------------------------------------------------------
// RoPE cos/sin table: [T][64] fp32, accurate sinf/cosf.
// ---------------------------------------------------------------------------
__global__ void k_rope_table(float* __restrict__ ct, float* __restrict__ st)
{
    int t = blockIdx.x, d = threadIdx.x;              // 1024 x 64
    float inv = expf(-(float)d * (9.210340371976184f / 64.0f)); // 10000^(-d/64)
    float th = (float)t * inv;
    ct[t * 64 + d] = cosf(th);
    st[t * 64 + d] = sinf(th);
}

// ---------------------------------------------------------------------------
// RoPE in-place on q,k (bto layout: [(b*T+t)*C + h*D + d], head dim contig).
// ---------------------------------------------------------------------------
__global__ __launch_bounds__(256) void k_rope(
    u16* __restrict__ q, u16* __restrict__ k,
    const float* __restrict__ ct, const float* __restrict__ st)
{
    int idx = blockIdx.x * 256 + threadIdx.x;  // b:1 | t:10 | h:4 | d:6
    int d = idx & 63;
    int h = (idx >> 6) & 15;
    int t = (idx >> 10) & 1023;
    int b = idx >> 20;
    size_t base = ((size_t)(b * T_ + t)) * C_ + h * D_ + d;
    float c = ct[t * 64 + d], s = st[t * 64 + d];
    float q0 = bf2f(q[base]), q1 = bf2f(q[base + 64]);
    q[base]      = f2bf(q0 * c - q1 * s);
    q[base + 64] = f2bf(q1 * c + q0 * s);
    float k0 = bf2f(k[base]), k1 = bf2f(k[base + 64]);
    k[base]      = f2bf(k0 * c - k1 * s);
    k[base + 64] = f2bf(k1 * c + k0 * s);
}

// ---------------------------------------------------------------------------
// Core 128x128 MFMA tile GEMM, bf16 inputs, fp32 accumulate.
//   TRANSB=false: B is [n][k] row-major (NT form: D = A * B^T)
//   TRANSB=true : B is [k][n] row-major (NN form), staged transposed into LDS
// LDS rows padded to 72 elems (+16B) to break 128B-stride bank aliasing.
// ---------------------------------------------------------------------------
template<bool TRANSB, typename OutT>
__device__ __forceinline__ void gemm_tile(
    const u16* __restrict__ A, int lda,
    const u16* __restrict__ Bp, int ldb,
    OutT* __restrict__ Cp, int ldc,
    int m0, int n0, int K, float scale,
    u16* As, u16* Bs)
{
    const int tid  = threadIdx.x;
    const int wave = tid >> 6;
    const int lane = tid & 63;
    const int wr   = (wave >> 1) << 6;   // wave sub-tile row offset (0/64)
    const int wc   = (wave & 1)  << 6;   // wave sub-tile col offset (0/64)
    const int frow = lane & 15;
    const int quad = lane >> 4;
    const int fk   = quad << 3;          // k element offset within 32-chunk

    f32x4 acc[4][4] = {};

    for (int kt = 0; kt < K; kt += 64) {
        // ---- stage A tile: 128 rows x 64 cols bf16 ----
#pragma unroll
        for (int i = 0; i < 4; ++i) {
            int c  = (i << 8) + tid;           // 0..1023 chunks of 8 elems
            int r  = c >> 3;
            int c8 = (c & 7) << 3;
            *(uint4*)&As[r * 72 + c8] =
                *(const uint4*)&A[(size_t)(m0 + r) * lda + kt + c8];
        }
        // ---- stage B tile ----
        if constexpr (!TRANSB) {
#pragma unroll
            for (int i = 0; i < 4; ++i) {
                int c  = (i << 8) + tid;
                int r  = c >> 3;
                int c8 = (c & 7) << 3;
                *(uint4*)&Bs[r * 72 + c8] =
                    *(const uint4*)&Bp[(size_t)(n0 + r) * ldb + kt + c8];
            }
        } else {
            // B is [k][n]; stage transposed -> Bs[n][k].
            // lane->k mapping keeps LDS scalar writes conflict-free.
#pragma unroll
            for (int i = 0; i < 4; ++i) {
                int c  = (i << 8) + tid;
                int kr = c & 63;
                int n8 = (c >> 6) << 3;
                uint4 vv = *(const uint4*)&Bp[(size_t)(kt + kr) * ldb + n8];
                u16 tmp[8];
                *(uint4*)tmp = vv;
#pragma unroll
                for (int e = 0; e < 8; ++e)
                    Bs[(n8 + e) * 72 + kr] = tmp[e];
            }
        }
        __syncthreads();

#pragma unroll
        for (int ks = 0; ks < 2; ++ks) {
            bf16x8 af[4], bfv[4];
#pragma unroll
            for (int i = 0; i < 4; ++i)
                af[i] = *(const bf16x8*)&As[(wr + (i << 4) + frow) * 72 + (ks << 5) + fk];
#pragma unroll
            for (int j = 0; j < 4; ++j)
                bfv[j] = *(const bf16x8*)&Bs[(wc + (j << 4) + frow) * 72 + (ks << 5) + fk];
#pragma unroll
            for (int i = 0; i < 4; ++i)
#pragma unroll
                for (int j = 0; j < 4; ++j)
                    acc[i][j] = __builtin_amdgcn_mfma_f32_16x16x32_bf16(
                        af[i], bfv[j], acc[i][j], 0, 0, 0);
        }
        __syncthreads();
    }

    // epilogue: C/D layout col=lane&15, row=quad*4+reg
#pragma unroll
    for (int i = 0; i < 4; ++i)
#pragma unroll
        for (int j = 0; j < 4; ++j)
#pragma unroll
            for (int r = 0; r < 4; ++r) {
                int m = m0 + wr + (i << 4) + (quad << 2) + r;
                int n = n0 + wc + (j << 4) + frow;
                float val = acc[i][j][r] * scale;
                if constexpr (sizeof(OutT) == 2)
                    Cp[(size_t)m * ldc + n] = f2bf(val);
                else
                    Cp[(size_t)m * ldc + n] = val;
            }
}

// ---------------------------------------------------------------------------
// QKV projection: z selects W and destination. out = x @ W^T, bf16 out (bto).
// ---------------------------------------------------------------------------
__global__ __launch_bounds__(256) void k_gemm_qkv(
    const u16* __restrict__ xb, const u16* __restrict__ wq,
    const u16* __restrict__ wk, const u16* __restrict__ wv,
    u16* __restrict__ q, u16* __restrict__ k, u16* __restrict__ v)
{
    __shared__ u16 As[128 * 72], Bs[128 * 72];
    int z = blockIdx.z;
    const u16* Bp = (z == 0) ? wq : (z == 1) ? wk : wv;
    u16* Op       = (z == 0) ? q  : (z == 1) ? k  : v;
    gemm_tile<false, u16>(xb, C_, Bp, C_, Op, C_,
                          blockIdx.y * 128, blockIdx.x * 128, C_, 1.0f, As, Bs);
}

// ---------------------------------------------------------------------------
// S = q @ k^T * scale per (b,h). Skip tiles fully above the diagonal.
// ---------------------------------------------------------------------------
__global__ __launch_bounds__(256) void k_gemm_qk(
    const u16* __restrict__ qb, const u16* __restrict__ kb, u16* __restrict__ S)
{
    __shared__ u16 As[128 * 72], Bs[128 * 72];
    int m0 = blockIdx.y * 128, n0 = blockIdx.x * 128;
    if (n0 > m0) return;                       // fully-masked tile
    int bh = blockIdx.z, b = bh >> 4, h = bh & 15;
    const u16* Ab = qb + (size_t)b * T_ * C_ + h * D_;
    const u16* Bb = kb + (size_t)b * T_ * C_ + h * D_;
    u16* Ob = S + ((size_t)bh << 20);
    gemm_tile<false, u16>(Ab, C_, Bb, C_, Ob, T_, m0, n0, D_,
                          0.08838834764831845f, As, Bs);   // 1/sqrt(128)
}

// ---------------------------------------------------------------------------
// Causal softmax, in-place on S. One wave per row; zero-fill to tile edge.
// ---------------------------------------------------------------------------
__global__ __launch_bounds__(256) void k_softmax(u16* __restrict__ S)
{
    int wv = threadIdx.x >> 6, lane = threadIdx.x & 63;
    int row = blockIdx.x * 4 + wv;             // 0 .. B*H*T-1
    int bh = row >> 10, t = row & 1023;
    u16* p = S + ((size_t)bh << 20) + ((size_t)t << 10);
    int L = t + 1;
    int limit = (t | 127) + 1;                 // next 128-aligned boundary

    float vals[16];
    float m = -1e30f;
#pragma unroll
    for (int it = 0; it < 16; ++it) {
        int j = lane + (it << 6);
        float v = -1e30f;
        if (j < L) v = bf2f(p[j]);
        vals[it] = v;
        m = fmaxf(m, v);
    }
#pragma unroll
    for (int off = 32; off > 0; off >>= 1) m = fmaxf(m, __shfl_xor(m, off));

    float sum = 0.0f;
#pragma unroll
    for (int it = 0; it < 16; ++it) {
        int j = lane + (it << 6);
        if (j < L) {
            float e = __expf(vals[it] - m);
            vals[it] = e;
            sum += e;
        }
    }
#pragma unroll
    for (int off = 32; off > 0; off >>= 1) sum += __shfl_xor(sum, off);
    float inv = 1.0f / sum;

#pragma unroll
    for (int it = 0; it < 16; ++it) {
        int j = lane + (it << 6);
        if (j < limit) p[j] = f2bf((j < L) ? vals[it] * inv : 0.0f);
    }
}

// ---------------------------------------------------------------------------
// y = P @ V per (b,h) (NN GEMM, V staged transposed). K_eff = m0+128 (causal).
// ---------------------------------------------------------------------------
__global__ __launch_bounds__(256) void k_gemm_pv(
    const u16* __restrict__ P, const u16* __restrict__ vb, u16* __restrict__ yb)
{
    __shared__ u16 As[128 * 72], Bs[128 * 72];
    int bh = blockIdx.z, b = bh >> 4, h = bh & 15;
    int m0 = blockIdx.y * 128;
    int Keff = m0 + 128;
    const u16* Ab = P + ((size_t)bh << 20);
    const u16* Bb = vb + (size_t)b * T_ * C_ + h * D_;
    u16* Ob = yb + (size_t)b * T_ * C_ + h * D_;
    gemm_tile<true, u16>(Ab, T_, Bb, C_, Ob, C_, m0, 0, Keff, 1.0f, As, Bs);
}

// ---------------------------------------------------------------------------
// out = y @ Wo^T, fp32 output.
// ---------------------------------------------------------------------------
__global__ __launch_bounds__(256) void k_gemm_out(
    const u16* __restrict__ yb, const u16* __restrict__ wo, float* __restrict__ out)
{
    __shared__ u16 As[128 * 72], Bs[128 * 72];
    gemm_tile<false, float>(yb, C_, wo, C_, out, C_,
                            blockIdx.y * 128, blockIdx.x * 128, C_, 1.0f, As, Bs);
}

// ---------------------------------------------------------------------------
extern "C" void kernel_launch(void* const* d_in, const int* in_sizes, int n_in,
                              void* d_out, int out_size, void* d_ws, size_t ws_size,
                              hipStream_t stream)
{
    (void)in_sizes; (void)n_in; (void)out_size; (void)ws_size;
    const float* x  = (const float*)d_in[0];
    const float* Wq = (const float*)d_in[1];
    const float* Wk = (const float*)d_in[2];
    const float* Wv = (const float*)d_in[3];
    const float* Wo = (const float*)d_in[4];

    u16* ws  = (u16*)d_ws;
    u16* xb  = ws;
    u16* wqb = ws + (size_t)1 * NTENS;
    u16* wkb = ws + (size_t)2 * NTENS;
    u16* wvb = ws + (size_t)3 * NTENS;
    u16* wob = ws + (size_t)4 * NTENS;
    u16* qb  = ws + (size_t)5 * NTENS;
    u16* kb  = ws + (size_t)6 * NTENS;
    u16* vb  = ws + (size_t)7 * NTENS;
    u16* yb  = ws + (size_t)8 * NTENS;
    u16* S   = ws + (size_t)9 * NTENS;                     // B*H*T*T bf16 = 64 MiB
    float* ct = (float*)(ws + (size_t)9 * NTENS + 33554432);
    float* st = ct + 65536;

    k_convert  <<<dim3(4096, 1, 5), 256, 0, stream>>>(x, Wq, Wk, Wv, Wo, ws);
    k_rope_table<<<dim3(1024), 64, 0, stream>>>(ct, st);
    k_gemm_qkv <<<dim3(16, 16, 3), 256, 0, stream>>>(xb, wqb, wkb, wvb, qb, kb, vb);
    k_rope     <<<dim3(8192), 256, 0, stream>>>(qb, kb, ct, st);
    k_gemm_qk  <<<dim3(8, 8, 32), 256, 0, stream>>>(qb, kb, S);
    k_softmax  <<<dim3(8192), 256, 0, stream>>>(S);
    k_gemm_pv  <<<dim3(1, 8, 32), 256, 0, stream>>>(S, vb, yb);
    k_gemm_out <<<dim3(16, 16, 1), 256, 0, stream>>>(yb, wob, (float*)d_out);
}

// Round 2
// 325.037 us; speedup vs baseline: 1.0353x; 1.0353x over previous
//
#include <hip/hip_runtime.h>
#include <stdint.h>

typedef unsigned short u16;
typedef __bf16 bf16x8 __attribute__((ext_vector_type(8)));
typedef float  f32x4  __attribute__((ext_vector_type(4)));

#define B_  2
#define T_  1024
#define C_  2048
#define H_  16
#define D_  128
#define NTENS 4194304   // elements in x and in each W (2*1024*2048 == 2048*2048)

__device__ __forceinline__ u16 f2bf(float f) {
    union { float f; uint32_t u; } v; v.f = f;
    uint32_t r = (v.u + 0x7FFFu + ((v.u >> 16) & 1u)) >> 16;
    return (u16)r;
}
__device__ __forceinline__ float bf2f(u16 h) {
    union { uint32_t u; float f; } v; v.u = ((uint32_t)h) << 16;
    return v.f;
}

// ---------------------------------------------------------------------------
// fp32 -> bf16 conversion: z selects {x, Wq, Wk, Wv, Wo}; dst is contiguous.
// ---------------------------------------------------------------------------
__global__ __launch_bounds__(256) void k_convert(
    const float* __restrict__ x, const float* __restrict__ wq,
    const float* __restrict__ wk, const float* __restrict__ wv,
    const float* __restrict__ wo, u16* __restrict__ dst)
{
    int z = blockIdx.z;
    const float* src = (z == 0) ? x : (z == 1) ? wq : (z == 2) ? wk : (z == 3) ? wv : wo;
    u16* d = dst + (size_t)z * NTENS;
    size_t i = ((size_t)blockIdx.x * 256 + threadIdx.x) * 4;
    float4 v = *(const float4*)(src + i);
    ushort4 o;
    o.x = f2bf(v.x); o.y = f2bf(v.y); o.z = f2bf(v.z); o.w = f2bf(v.w);
    *(ushort4*)(d + i) = o;
}

// ---------------------------------------------------------------------------
// RoPE cos/sin table: [T][64] fp32, accurate sinf/cosf.
// ---------------------------------------------------------------------------
__global__ void k_rope_table(float* __restrict__ ct, float* __restrict__ st)
{
    int t = blockIdx.x, d = threadIdx.x;              // 1024 x 64
    float inv = expf(-(float)d * (9.210340371976184f / 64.0f)); // 10000^(-d/64)
    float th = (float)t * inv;
    ct[t * 64 + d] = cosf(th);
    st[t * 64 + d] = sinf(th);
}

// ---------------------------------------------------------------------------
// RoPE in-place on q,k (bto layout: [(b*T+t)*C + h*D + d], head dim contig).
// ---------------------------------------------------------------------------
__global__ __launch_bounds__(256) void k_rope(
    u16* __restrict__ q, u16* __restrict__ k,
    const float* __restrict__ ct, const float* __restrict__ st)
{
    int idx = blockIdx.x * 256 + threadIdx.x;  // b:1 | t:10 | h:4 | d:6
    int d = idx & 63;
    int h = (idx >> 6) & 15;
    int t = (idx >> 10) & 1023;
    int b = idx >> 20;
    size_t base = ((size_t)(b * T_ + t)) * C_ + h * D_ + d;
    float c = ct[t * 64 + d], s = st[t * 64 + d];
    float q0 = bf2f(q[base]), q1 = bf2f(q[base + 64]);
    q[base]      = f2bf(q0 * c - q1 * s);
    q[base + 64] = f2bf(q1 * c + q0 * s);
    float k0 = bf2f(k[base]), k1 = bf2f(k[base + 64]);
    k[base]      = f2bf(k0 * c - k1 * s);
    k[base + 64] = f2bf(k1 * c + k0 * s);
}

// ---------------------------------------------------------------------------
// NT-form 128x128 MFMA tile GEMM with async global->LDS staging.
//   A: [m][k] row-major, B: [n][k] row-major, D = A*B^T.
// LDS layout: unpadded [128][64], chunk c (=1KB, 8 rows) filled by one
// global_load_lds_dwordx4 per wave; lane l -> row c*8+(l>>3), slot l&7.
// XOR swizzle: slot s of row r holds global col-chunk s^(r&7) so fragment
// reads hit 8 distinct bank groups per quad (2-way aliasing = free).
// ---------------------------------------------------------------------------
template<typename OutT>
__device__ __forceinline__ void gemm_tile_nt(
    const u16* __restrict__ A, int lda,
    const u16* __restrict__ Bp, int ldb,
    OutT* __restrict__ Cp, int ldc,
    int m0, int n0, int K, float scale,
    u16* As, u16* Bs)
{
    const int tid  = threadIdx.x;
    const int wave = tid >> 6;
    const int lane = tid & 63;
    const int wr   = (wave >> 1) << 6;   // wave sub-tile row offset (0/64)
    const int wc   = (wave & 1)  << 6;   // wave sub-tile col offset (0/64)
    const int frow = lane & 15;
    const int quad = lane >> 4;

    const int lrow8  = lane >> 3;        // 0..7: row within 8-row chunk
    const int slot   = lane & 7;         // 0..7: LDS 16B slot within row
    const int gchunk = slot ^ lrow8;     // XOR-swizzled global col chunk

    f32x4 acc[4][4] = {};

    size_t aoff[4], boff[4];
#pragma unroll
    for (int i = 0; i < 4; ++i) {
        int r = (i << 5) + (wave << 3) + lrow8;     // global tile row 0..127
        aoff[i] = (size_t)(m0 + r) * lda + (gchunk << 3);
        boff[i] = (size_t)(n0 + r) * ldb + (gchunk << 3);
    }

    for (int kt = 0; kt < K; kt += 64) {
#pragma unroll
        for (int i = 0; i < 4; ++i) {
            int c = (i << 2) + wave;                // LDS chunk index 0..15
            __builtin_amdgcn_global_load_lds(
                (const __attribute__((address_space(1))) void*)(A + aoff[i] + kt),
                (__attribute__((address_space(3))) void*)(As + (c << 9)), 16, 0, 0);
            __builtin_amdgcn_global_load_lds(
                (const __attribute__((address_space(1))) void*)(Bp + boff[i] + kt),
                (__attribute__((address_space(3))) void*)(Bs + (c << 9)), 16, 0, 0);
        }
        __syncthreads();

#pragma unroll
        for (int ks = 0; ks < 2; ++ks) {
            bf16x8 af[4], bfv[4];
#pragma unroll
            for (int i = 0; i < 4; ++i) {
                int ar = wr + (i << 4) + frow;
                int lk = (ks << 2) + quad;          // logical col chunk 0..7
                af[i] = *(const bf16x8*)&As[ar * 64 + ((lk ^ (frow & 7)) << 3)];
            }
#pragma unroll
            for (int j = 0; j < 4; ++j) {
                int br = wc + (j << 4) + frow;
                int lk = (ks << 2) + quad;
                bfv[j] = *(const bf16x8*)&Bs[br * 64 + ((lk ^ (frow & 7)) << 3)];
            }
#pragma unroll
            for (int i = 0; i < 4; ++i)
#pragma unroll
                for (int j = 0; j < 4; ++j)
                    acc[i][j] = __builtin_amdgcn_mfma_f32_16x16x32_bf16(
                        af[i], bfv[j], acc[i][j], 0, 0, 0);
        }
        __syncthreads();
    }

    // epilogue: C/D layout col=lane&15, row=quad*4+reg
#pragma unroll
    for (int i = 0; i < 4; ++i)
#pragma unroll
        for (int j = 0; j < 4; ++j)
#pragma unroll
            for (int r = 0; r < 4; ++r) {
                int m = m0 + wr + (i << 4) + (quad << 2) + r;
                int n = n0 + wc + (j << 4) + frow;
                float val = acc[i][j][r] * scale;
                if constexpr (sizeof(OutT) == 2)
                    Cp[(size_t)m * ldc + n] = f2bf(val);
                else
                    Cp[(size_t)m * ldc + n] = val;
            }
}

// ---------------------------------------------------------------------------
// Legacy padded-LDS tile GEMM (VGPR staging), used only for PV (B transposed).
// ---------------------------------------------------------------------------
template<bool TRANSB, typename OutT>
__device__ __forceinline__ void gemm_tile(
    const u16* __restrict__ A, int lda,
    const u16* __restrict__ Bp, int ldb,
    OutT* __restrict__ Cp, int ldc,
    int m0, int n0, int K, float scale,
    u16* As, u16* Bs)
{
    const int tid  = threadIdx.x;
    const int wave = tid >> 6;
    const int lane = tid & 63;
    const int wr   = (wave >> 1) << 6;
    const int wc   = (wave & 1)  << 6;
    const int frow = lane & 15;
    const int quad = lane >> 4;
    const int fk   = quad << 3;

    f32x4 acc[4][4] = {};

    for (int kt = 0; kt < K; kt += 64) {
#pragma unroll
        for (int i = 0; i < 4; ++i) {
            int c  = (i << 8) + tid;
            int r  = c >> 3;
            int c8 = (c & 7) << 3;
            *(uint4*)&As[r * 72 + c8] =
                *(const uint4*)&A[(size_t)(m0 + r) * lda + kt + c8];
        }
        if constexpr (!TRANSB) {
#pragma unroll
            for (int i = 0; i < 4; ++i) {
                int c  = (i << 8) + tid;
                int r  = c >> 3;
                int c8 = (c & 7) << 3;
                *(uint4*)&Bs[r * 72 + c8] =
                    *(const uint4*)&Bp[(size_t)(n0 + r) * ldb + kt + c8];
            }
        } else {
#pragma unroll
            for (int i = 0; i < 4; ++i) {
                int c  = (i << 8) + tid;
                int kr = c & 63;
                int n8 = (c >> 6) << 3;
                uint4 vv = *(const uint4*)&Bp[(size_t)(kt + kr) * ldb + n8];
                u16 tmp[8];
                *(uint4*)tmp = vv;
#pragma unroll
                for (int e = 0; e < 8; ++e)
                    Bs[(n8 + e) * 72 + kr] = tmp[e];
            }
        }
        __syncthreads();

#pragma unroll
        for (int ks = 0; ks < 2; ++ks) {
            bf16x8 af[4], bfv[4];
#pragma unroll
            for (int i = 0; i < 4; ++i)
                af[i] = *(const bf16x8*)&As[(wr + (i << 4) + frow) * 72 + (ks << 5) + fk];
#pragma unroll
            for (int j = 0; j < 4; ++j)
                bfv[j] = *(const bf16x8*)&Bs[(wc + (j << 4) + frow) * 72 + (ks << 5) + fk];
#pragma unroll
            for (int i = 0; i < 4; ++i)
#pragma unroll
                for (int j = 0; j < 4; ++j)
                    acc[i][j] = __builtin_amdgcn_mfma_f32_16x16x32_bf16(
                        af[i], bfv[j], acc[i][j], 0, 0, 0);
        }
        __syncthreads();
    }

#pragma unroll
    for (int i = 0; i < 4; ++i)
#pragma unroll
        for (int j = 0; j < 4; ++j)
#pragma unroll
            for (int r = 0; r < 4; ++r) {
                int m = m0 + wr + (i << 4) + (quad << 2) + r;
                int n = n0 + wc + (j << 4) + frow;
                float val = acc[i][j][r] * scale;
                if constexpr (sizeof(OutT) == 2)
                    Cp[(size_t)m * ldc + n] = f2bf(val);
                else
                    Cp[(size_t)m * ldc + n] = val;
            }
}

// ---------------------------------------------------------------------------
// QKV projection: z selects W and destination. out = x @ W^T, bf16 out (bto).
// ---------------------------------------------------------------------------
__global__ __launch_bounds__(256) void k_gemm_qkv(
    const u16* __restrict__ xb, const u16* __restrict__ wq,
    const u16* __restrict__ wk, const u16* __restrict__ wv,
    u16* __restrict__ q, u16* __restrict__ k, u16* __restrict__ v)
{
    __shared__ u16 As[128 * 64], Bs[128 * 64];
    int z = blockIdx.z;
    const u16* Bp = (z == 0) ? wq : (z == 1) ? wk : wv;
    u16* Op       = (z == 0) ? q  : (z == 1) ? k  : v;
    gemm_tile_nt<u16>(xb, C_, Bp, C_, Op, C_,
                      blockIdx.y * 128, blockIdx.x * 128, C_, 1.0f, As, Bs);
}

// ---------------------------------------------------------------------------
// S = q @ k^T * scale per (b,h). Skip tiles fully above the diagonal.
// ---------------------------------------------------------------------------
__global__ __launch_bounds__(256) void k_gemm_qk(
    const u16* __restrict__ qb, const u16* __restrict__ kb, u16* __restrict__ S)
{
    __shared__ u16 As[128 * 64], Bs[128 * 64];
    int m0 = blockIdx.y * 128, n0 = blockIdx.x * 128;
    if (n0 > m0) return;                       // fully-masked tile
    int bh = blockIdx.z, b = bh >> 4, h = bh & 15;
    const u16* Ab = qb + (size_t)b * T_ * C_ + h * D_;
    const u16* Bb = kb + (size_t)b * T_ * C_ + h * D_;
    u16* Ob = S + ((size_t)bh << 20);
    gemm_tile_nt<u16>(Ab, C_, Bb, C_, Ob, T_, m0, n0, D_,
                      0.08838834764831845f, As, Bs);   // 1/sqrt(128)
}

// ---------------------------------------------------------------------------
// Causal softmax, in-place on S. One wave per row; zero-fill to tile edge.
// ---------------------------------------------------------------------------
__global__ __launch_bounds__(256) void k_softmax(u16* __restrict__ S)
{
    int wv = threadIdx.x >> 6, lane = threadIdx.x & 63;
    int row = blockIdx.x * 4 + wv;             // 0 .. B*H*T-1
    int bh = row >> 10, t = row & 1023;
    u16* p = S + ((size_t)bh << 20) + ((size_t)t << 10);
    int L = t + 1;
    int limit = (t | 127) + 1;                 // next 128-aligned boundary

    float vals[16];
    float m = -1e30f;
#pragma unroll
    for (int it = 0; it < 16; ++it) {
        int j = lane + (it << 6);
        float v = -1e30f;
        if (j < L) v = bf2f(p[j]);
        vals[it] = v;
        m = fmaxf(m, v);
    }
#pragma unroll
    for (int off = 32; off > 0; off >>= 1) m = fmaxf(m, __shfl_xor(m, off));

    float sum = 0.0f;
#pragma unroll
    for (int it = 0; it < 16; ++it) {
        int j = lane + (it << 6);
        if (j < L) {
            float e = __expf(vals[it] - m);
            vals[it] = e;
            sum += e;
        }
    }
#pragma unroll
    for (int off = 32; off > 0; off >>= 1) sum += __shfl_xor(sum, off);
    float inv = 1.0f / sum;

#pragma unroll
    for (int it = 0; it < 16; ++it) {
        int j = lane + (it << 6);
        if (j < limit) p[j] = f2bf((j < L) ? vals[it] * inv : 0.0f);
    }
}

// ---------------------------------------------------------------------------
// y = P @ V per (b,h) (NN GEMM, V staged transposed). K_eff = m0+128 (causal).
// ---------------------------------------------------------------------------
__global__ __launch_bounds__(256) void k_gemm_pv(
    const u16* __restrict__ P, const u16* __restrict__ vb, u16* __restrict__ yb)
{
    __shared__ u16 As[128 * 72], Bs[128 * 72];
    int bh = blockIdx.z, b = bh >> 4, h = bh & 15;
    int m0 = blockIdx.y * 128;
    int Keff = m0 + 128;
    const u16* Ab = P + ((size_t)bh << 20);
    const u16* Bb = vb + (size_t)b * T_ * C_ + h * D_;
    u16* Ob = yb + (size_t)b * T_ * C_ + h * D_;
    gemm_tile<true, u16>(Ab, T_, Bb, C_, Ob, C_, m0, 0, Keff, 1.0f, As, Bs);
}

// ---------------------------------------------------------------------------
// out = y @ Wo^T, fp32 output.
// ---------------------------------------------------------------------------
__global__ __launch_bounds__(256) void k_gemm_out(
    const u16* __restrict__ yb, const u16* __restrict__ wo, float* __restrict__ out)
{
    __shared__ u16 As[128 * 64], Bs[128 * 64];
    gemm_tile_nt<float>(yb, C_, wo, C_, out, C_,
                        blockIdx.y * 128, blockIdx.x * 128, C_, 1.0f, As, Bs);
}

// ---------------------------------------------------------------------------
extern "C" void kernel_launch(void* const* d_in, const int* in_sizes, int n_in,
                              void* d_out, int out_size, void* d_ws, size_t ws_size,
                              hipStream_t stream)
{
    (void)in_sizes; (void)n_in; (void)out_size; (void)ws_size;
    const float* x  = (const float*)d_in[0];
    const float* Wq = (const float*)d_in[1];
    const float* Wk = (const float*)d_in[2];
    const float* Wv = (const float*)d_in[3];
    const float* Wo = (const float*)d_in[4];

    u16* ws  = (u16*)d_ws;
    u16* xb  = ws;
    u16* wqb = ws + (size_t)1 * NTENS;
    u16* wkb = ws + (size_t)2 * NTENS;
    u16* wvb = ws + (size_t)3 * NTENS;
    u16* wob = ws + (size_t)4 * NTENS;
    u16* qb  = ws + (size_t)5 * NTENS;
    u16* kb  = ws + (size_t)6 * NTENS;
    u16* vb  = ws + (size_t)7 * NTENS;
    u16* yb  = ws + (size_t)8 * NTENS;
    u16* S   = ws + (size_t)9 * NTENS;                     // B*H*T*T bf16 = 64 MiB
    float* ct = (float*)(ws + (size_t)9 * NTENS + 33554432);
    float* st = ct + 65536;

    k_convert  <<<dim3(4096, 1, 5), 256, 0, stream>>>(x, Wq, Wk, Wv, Wo, ws);
    k_rope_table<<<dim3(1024), 64, 0, stream>>>(ct, st);
    k_gemm_qkv <<<dim3(16, 16, 3), 256, 0, stream>>>(xb, wqb, wkb, wvb, qb, kb, vb);
    k_rope     <<<dim3(8192), 256, 0, stream>>>(qb, kb, ct, st);
    k_gemm_qk  <<<dim3(8, 8, 32), 256, 0, stream>>>(qb, kb, S);
    k_softmax  <<<dim3(8192), 256, 0, stream>>>(S);
    k_gemm_pv  <<<dim3(1, 8, 32), 256, 0, stream>>>(S, vb, yb);
    k_gemm_out <<<dim3(16, 16, 1), 256, 0, stream>>>(yb, wob, (float*)d_out);
}

// Round 3
// 285.758 us; speedup vs baseline: 1.1776x; 1.1375x over previous
//
#include <hip/hip_runtime.h>
#include <stdint.h>

typedef unsigned short u16;
typedef __bf16 bf16x8 __attribute__((ext_vector_type(8)));
typedef float  f32x4  __attribute__((ext_vector_type(4)));

#define B_  2
#define T_  1024
#define C_  2048
#define H_  16
#define D_  128
#define NTENS 4194304   // elements in x and in each W (2*1024*2048 == 2048*2048)

__device__ __forceinline__ u16 f2bf(float f) {
    union { float f; uint32_t u; } v; v.f = f;
    uint32_t r = (v.u + 0x7FFFu + ((v.u >> 16) & 1u)) >> 16;
    return (u16)r;
}
__device__ __forceinline__ float bf2f(u16 h) {
    union { uint32_t u; float f; } v; v.u = ((uint32_t)h) << 16;
    return v.f;
}

// ---------------------------------------------------------------------------
// fp32 -> bf16 conversion: z selects {x, Wq, Wk, Wv, Wo}; dst is contiguous.
// ---------------------------------------------------------------------------
__global__ __launch_bounds__(256) void k_convert(
    const float* __restrict__ x, const float* __restrict__ wq,
    const float* __restrict__ wk, const float* __restrict__ wv,
    const float* __restrict__ wo, u16* __restrict__ dst)
{
    int z = blockIdx.z;
    const float* src = (z == 0) ? x : (z == 1) ? wq : (z == 2) ? wk : (z == 3) ? wv : wo;
    u16* d = dst + (size_t)z * NTENS;
    size_t i = ((size_t)blockIdx.x * 256 + threadIdx.x) * 4;
    float4 v = *(const float4*)(src + i);
    ushort4 o;
    o.x = f2bf(v.x); o.y = f2bf(v.y); o.z = f2bf(v.z); o.w = f2bf(v.w);
    *(ushort4*)(d + i) = o;
}

// ---------------------------------------------------------------------------
// RoPE in-place on q,k (bto layout), trig computed inline. Also folds the
// 1/sqrt(D) attention scale into q.
// ---------------------------------------------------------------------------
__global__ __launch_bounds__(256) void k_rope(
    u16* __restrict__ q, u16* __restrict__ k)
{
    int idx = blockIdx.x * 256 + threadIdx.x;  // b:1 | t:10 | h:4 | d:6
    int d = idx & 63;
    int h = (idx >> 6) & 15;
    int t = (idx >> 10) & 1023;
    int b = idx >> 20;
    size_t base = ((size_t)(b * T_ + t)) * C_ + h * D_ + d;
    float inv = expf(-(float)d * (9.210340371976184f / 64.0f)); // 10000^(-d/64)
    float th = (float)t * inv;
    float s, c;
    sincosf(th, &s, &c);
    const float sc = 0.08838834764831845f;     // 1/sqrt(128)
    float q0 = bf2f(q[base]), q1 = bf2f(q[base + 64]);
    q[base]      = f2bf((q0 * c - q1 * s) * sc);
    q[base + 64] = f2bf((q1 * c + q0 * s) * sc);
    float k0 = bf2f(k[base]), k1 = bf2f(k[base + 64]);
    k[base]      = f2bf(k0 * c - k1 * s);
    k[base + 64] = f2bf(k1 * c + k0 * s);
}

// ---------------------------------------------------------------------------
// V transpose: vb [b,t,h,d] -> vt [bh][d][t]   (so flash can stage V tiles
// k-major with global_load_lds).
// ---------------------------------------------------------------------------
__global__ __launch_bounds__(256) void k_transpose_v(
    const u16* __restrict__ vb, u16* __restrict__ vt)
{
    __shared__ u16 L[64 * 136];
    int t0 = blockIdx.x << 6;                  // 16 t-tiles of 64
    int bh = blockIdx.y, b = bh >> 4, h = bh & 15;
    const u16* src = vb + (size_t)b * (T_ * C_) + h * D_;
    u16* dst = vt + (size_t)bh * (D_ * T_);
    int tid = threadIdx.x;
#pragma unroll
    for (int i = 0; i < 4; ++i) {
        int idx = (i << 8) + tid;              // 0..1023 uint4 chunks
        int r = idx >> 4, s = idx & 15;
        *(uint4*)&L[r * 136 + (s << 3)] =
            *(const uint4*)&src[(size_t)(t0 + r) * C_ + (s << 3)];
    }
    __syncthreads();
#pragma unroll
    for (int i = 0; i < 8; ++i) {
        int idx = (i << 8) + tid;              // 0..2047 groups of 4 t
        int d = idx >> 4, s = idx & 15;
        int t = s << 2;
        ushort4 o;
        o.x = L[(t    ) * 136 + d];
        o.y = L[(t + 1) * 136 + d];
        o.z = L[(t + 2) * 136 + d];
        o.w = L[(t + 3) * 136 + d];
        *(ushort4*)&dst[(size_t)d * T_ + t0 + t] = o;
    }
}

// ---------------------------------------------------------------------------
// NT-form 128x128 MFMA tile GEMM with async global->LDS staging (unchanged
// from R2; XOR-swizzled LDS, zero bank conflicts).
// ---------------------------------------------------------------------------
template<typename OutT>
__device__ __forceinline__ void gemm_tile_nt(
    const u16* __restrict__ A, int lda,
    const u16* __restrict__ Bp, int ldb,
    OutT* __restrict__ Cp, int ldc,
    int m0, int n0, int K, float scale,
    u16* As, u16* Bs)
{
    const int tid  = threadIdx.x;
    const int wave = tid >> 6;
    const int lane = tid & 63;
    const int wr   = (wave >> 1) << 6;
    const int wc   = (wave & 1)  << 6;
    const int frow = lane & 15;
    const int quad = lane >> 4;

    const int lrow8  = lane >> 3;
    const int slot   = lane & 7;
    const int gchunk = slot ^ lrow8;

    f32x4 acc[4][4] = {};

    size_t aoff[4], boff[4];
#pragma unroll
    for (int i = 0; i < 4; ++i) {
        int r = (i << 5) + (wave << 3) + lrow8;
        aoff[i] = (size_t)(m0 + r) * lda + (gchunk << 3);
        boff[i] = (size_t)(n0 + r) * ldb + (gchunk << 3);
    }

    for (int kt = 0; kt < K; kt += 64) {
#pragma unroll
        for (int i = 0; i < 4; ++i) {
            int c = (i << 2) + wave;
            __builtin_amdgcn_global_load_lds(
                (const __attribute__((address_space(1))) void*)(A + aoff[i] + kt),
                (__attribute__((address_space(3))) void*)(As + (c << 9)), 16, 0, 0);
            __builtin_amdgcn_global_load_lds(
                (const __attribute__((address_space(1))) void*)(Bp + boff[i] + kt),
                (__attribute__((address_space(3))) void*)(Bs + (c << 9)), 16, 0, 0);
        }
        __syncthreads();

#pragma unroll
        for (int ks = 0; ks < 2; ++ks) {
            bf16x8 af[4], bfv[4];
#pragma unroll
            for (int i = 0; i < 4; ++i) {
                int ar = wr + (i << 4) + frow;
                int lk = (ks << 2) + quad;
                af[i] = *(const bf16x8*)&As[ar * 64 + ((lk ^ (frow & 7)) << 3)];
            }
#pragma unroll
            for (int j = 0; j < 4; ++j) {
                int br = wc + (j << 4) + frow;
                int lk = (ks << 2) + quad;
                bfv[j] = *(const bf16x8*)&Bs[br * 64 + ((lk ^ (frow & 7)) << 3)];
            }
#pragma unroll
            for (int i = 0; i < 4; ++i)
#pragma unroll
                for (int j = 0; j < 4; ++j)
                    acc[i][j] = __builtin_amdgcn_mfma_f32_16x16x32_bf16(
                        af[i], bfv[j], acc[i][j], 0, 0, 0);
        }
        __syncthreads();
    }

#pragma unroll
    for (int i = 0; i < 4; ++i)
#pragma unroll
        for (int j = 0; j < 4; ++j)
#pragma unroll
            for (int r = 0; r < 4; ++r) {
                int m = m0 + wr + (i << 4) + (quad << 2) + r;
                int n = n0 + wc + (j << 4) + frow;
                float val = acc[i][j][r] * scale;
                if constexpr (sizeof(OutT) == 2)
                    Cp[(size_t)m * ldc + n] = f2bf(val);
                else
                    Cp[(size_t)m * ldc + n] = val;
            }
}

// ---------------------------------------------------------------------------
// QKV projection: z selects W and destination. out = x @ W^T, bf16 out (bto).
// ---------------------------------------------------------------------------
__global__ __launch_bounds__(256) void k_gemm_qkv(
    const u16* __restrict__ xb, const u16* __restrict__ wq,
    const u16* __restrict__ wk, const u16* __restrict__ wv,
    u16* __restrict__ q, u16* __restrict__ k, u16* __restrict__ v)
{
    __shared__ u16 As[128 * 64], Bs[128 * 64];
    int z = blockIdx.z;
    const u16* Bp = (z == 0) ? wq : (z == 1) ? wk : wv;
    u16* Op       = (z == 0) ? q  : (z == 1) ? k  : v;
    gemm_tile_nt<u16>(xb, C_, Bp, C_, Op, C_,
                      blockIdx.y * 128, blockIdx.x * 128, C_, 1.0f, As, Bs);
}

// ---------------------------------------------------------------------------
// Fused flash attention: S = qK^T (q pre-scaled), online softmax, Y = P V.
// Grid: 512 blocks = 16 q-tiles(64 rows) x 32 bh; heavy q-tiles dispatched
// first (LPT balance). Block 256 threads = 4 waves; wave-tile = 16 rows.
// LDS 48 KB: Qs 64x128, Ks 64x128 (reused as P, stride 72), Vs 128x64 (V^T).
// ---------------------------------------------------------------------------
__global__ __launch_bounds__(256) void k_flash(
    const u16* __restrict__ qb, const u16* __restrict__ kb,
    const u16* __restrict__ vt, u16* __restrict__ yb)
{
    __shared__ u16 Qs[64 * 128];
    __shared__ u16 Ks[64 * 128];   // reused as P after B2
    __shared__ u16 Vs[128 * 64];

    const int bx  = blockIdx.x;
    const int bh  = bx & 31, b = bh >> 4, h = bh & 15;
    const int qt  = 15 - (bx >> 5);           // heavy tiles first
    const int tid = threadIdx.x, wave = tid >> 6, lane = tid & 63;
    const int frow = lane & 15, quad = lane >> 4;

    const u16* qbase = qb + (size_t)b * (T_ * C_) + h * D_;
    const u16* kbase = kb + (size_t)b * (T_ * C_) + h * D_;
    const u16* vbase = vt + (size_t)bh * (D_ * T_);
    const int q0 = qt << 6;

    // ---- stage Q tile (64 rows x 128 d), XOR-swizzled 16B slots ----
    {
        const int r4 = lane >> 4, s16 = lane & 15;
#pragma unroll
        for (int i = 0; i < 4; ++i) {
            int c = (i << 2) + wave;                 // chunk = 4 rows
            int row = (c << 2) + r4;
            int g = (s16 & 8) | ((s16 & 7) ^ (row & 7));
            __builtin_amdgcn_global_load_lds(
                (const __attribute__((address_space(1))) void*)(qbase + (size_t)(q0 + row) * C_ + (g << 3)),
                (__attribute__((address_space(3))) void*)(Qs + (c << 9)), 16, 0, 0);
        }
    }

    f32x4 Y[8] = {};
    float mrow[4], lrow[4];
#pragma unroll
    for (int r = 0; r < 4; ++r) { mrow[r] = -3e38f; lrow[r] = 0.f; }

    const int tok = q0 + wave * 16 + quad * 4;       // + r = global row

    for (int kt = 0; kt <= qt; ++kt) {
        const int k0 = kt << 6;
        // ---- stage K tile (64x128) and V^T tile (128x64) ----
        {
            const int r4 = lane >> 4, s16 = lane & 15;
            const int r8 = lane >> 3, s8 = lane & 7;
#pragma unroll
            for (int i = 0; i < 4; ++i) {
                int c = (i << 2) + wave;
                int row = (c << 2) + r4;
                int g = (s16 & 8) | ((s16 & 7) ^ (row & 7));
                __builtin_amdgcn_global_load_lds(
                    (const __attribute__((address_space(1))) void*)(kbase + (size_t)(k0 + row) * C_ + (g << 3)),
                    (__attribute__((address_space(3))) void*)(Ks + (c << 9)), 16, 0, 0);
                int vrow = (c << 3) + r8;            // d index, 8 rows/chunk
                int vg = s8 ^ (vrow & 7);
                __builtin_amdgcn_global_load_lds(
                    (const __attribute__((address_space(1))) void*)(vbase + (size_t)vrow * T_ + k0 + (vg << 3)),
                    (__attribute__((address_space(3))) void*)(Vs + (c << 9)), 16, 0, 0);
            }
        }
        __syncthreads();   // B1: tiles staged (covers Q on first iter)

        // ---- S = q K^T  (wave-tile 16 x 64) ----
        f32x4 S[4] = {};
#pragma unroll
        for (int ks = 0; ks < 4; ++ks) {
            int lk = (ks << 2) + quad;
            int sw = ((lk & 8) | ((lk & 7) ^ (frow & 7))) << 3;
            bf16x8 a = *(const bf16x8*)&Qs[(wave * 16 + frow) * 128 + sw];
#pragma unroll
            for (int jj = 0; jj < 4; ++jj) {
                bf16x8 bb = *(const bf16x8*)&Ks[((jj << 4) + frow) * 128 + sw];
                S[jj] = __builtin_amdgcn_mfma_f32_16x16x32_bf16(a, bb, S[jj], 0, 0, 0);
            }
        }

        // ---- causal mask (diagonal tile only) ----
        if (kt == qt) {
#pragma unroll
            for (int jj = 0; jj < 4; ++jj) {
                int colg = k0 + (jj << 4) + frow;
#pragma unroll
                for (int r = 0; r < 4; ++r)
                    if (colg > tok + r) S[jj][r] = -1e30f;
            }
        }

        // ---- online softmax (rows live in 16-lane frow groups) ----
        float al[4];
#pragma unroll
        for (int r = 0; r < 4; ++r) {
            float tm = fmaxf(fmaxf(S[0][r], S[1][r]), fmaxf(S[2][r], S[3][r]));
#pragma unroll
            for (int off = 8; off > 0; off >>= 1) tm = fmaxf(tm, __shfl_xor(tm, off));
            float mn = fmaxf(mrow[r], tm);
            al[r] = __expf(mrow[r] - mn);
            mrow[r] = mn;
            float rs = 0.f;
#pragma unroll
            for (int jj = 0; jj < 4; ++jj) {
                float e = __expf(S[jj][r] - mn);
                S[jj][r] = e;
                rs += e;
            }
#pragma unroll
            for (int off = 8; off > 0; off >>= 1) rs += __shfl_xor(rs, off);
            lrow[r] = lrow[r] * al[r] + rs;
        }
#pragma unroll
        for (int dj = 0; dj < 8; ++dj)
#pragma unroll
            for (int r = 0; r < 4; ++r) Y[dj][r] *= al[r];

        __syncthreads();   // B2: all waves done reading Ks -> safe to overwrite

        // ---- write P into Ks region (A-layout, stride 72, wave-local rows) ----
        u16* Ps = Ks;
#pragma unroll
        for (int jj = 0; jj < 4; ++jj)
#pragma unroll
            for (int r = 0; r < 4; ++r)
                Ps[(wave * 16 + quad * 4 + r) * 72 + (jj << 4) + frow] = f2bf(S[jj][r]);

        // ---- Y += P V ----
#pragma unroll
        for (int ks = 0; ks < 2; ++ks) {
            bf16x8 pa = *(const bf16x8*)&Ps[(wave * 16 + frow) * 72 + (ks << 5) + (quad << 3)];
            int lk = (ks << 2) + quad;
#pragma unroll
            for (int dj = 0; dj < 8; ++dj) {
                bf16x8 vv = *(const bf16x8*)&Vs[((dj << 4) + frow) * 64 + ((lk ^ (frow & 7)) << 3)];
                Y[dj] = __builtin_amdgcn_mfma_f32_16x16x32_bf16(pa, vv, Y[dj], 0, 0, 0);
            }
        }
        __syncthreads();   // B3: PV reads done before next-iter staging
    }

    // ---- epilogue: Y /= l, store to yb [b,t,h,d] ----
    u16* ybase = yb + (size_t)b * (T_ * C_) + h * D_;
#pragma unroll
    for (int r = 0; r < 4; ++r) {
        float inv = 1.0f / lrow[r];
#pragma unroll
        for (int dj = 0; dj < 8; ++dj)
            ybase[(size_t)(tok + r) * C_ + (dj << 4) + frow] = f2bf(Y[dj][r] * inv);
    }
}

// ---------------------------------------------------------------------------
// out = y @ Wo^T, fp32 output.
// ---------------------------------------------------------------------------
__global__ __launch_bounds__(256) void k_gemm_out(
    const u16* __restrict__ yb, const u16* __restrict__ wo, float* __restrict__ out)
{
    __shared__ u16 As[128 * 64], Bs[128 * 64];
    gemm_tile_nt<float>(yb, C_, wo, C_, out, C_,
                        blockIdx.y * 128, blockIdx.x * 128, C_, 1.0f, As, Bs);
}

// ---------------------------------------------------------------------------
extern "C" void kernel_launch(void* const* d_in, const int* in_sizes, int n_in,
                              void* d_out, int out_size, void* d_ws, size_t ws_size,
                              hipStream_t stream)
{
    (void)in_sizes; (void)n_in; (void)out_size; (void)ws_size;
    const float* x  = (const float*)d_in[0];
    const float* Wq = (const float*)d_in[1];
    const float* Wk = (const float*)d_in[2];
    const float* Wv = (const float*)d_in[3];
    const float* Wo = (const float*)d_in[4];

    u16* ws  = (u16*)d_ws;
    u16* xb  = ws;
    u16* wqb = ws + (size_t)1 * NTENS;
    u16* wkb = ws + (size_t)2 * NTENS;
    u16* wvb = ws + (size_t)3 * NTENS;
    u16* wob = ws + (size_t)4 * NTENS;
    u16* qb  = ws + (size_t)5 * NTENS;
    u16* kb  = ws + (size_t)6 * NTENS;
    u16* vb  = ws + (size_t)7 * NTENS;
    u16* yb  = ws + (size_t)8 * NTENS;
    u16* vt  = ws + (size_t)9 * NTENS;         // [bh][d][t] = 4M elems

    k_convert    <<<dim3(4096, 1, 5), 256, 0, stream>>>(x, Wq, Wk, Wv, Wo, ws);
    k_gemm_qkv   <<<dim3(16, 16, 3), 256, 0, stream>>>(xb, wqb, wkb, wvb, qb, kb, vb);
    k_rope       <<<dim3(8192), 256, 0, stream>>>(qb, kb);
    k_transpose_v<<<dim3(16, 32), 256, 0, stream>>>(vb, vt);
    k_flash      <<<dim3(512), 256, 0, stream>>>(qb, kb, vt, yb);
    k_gemm_out   <<<dim3(16, 16, 1), 256, 0, stream>>>(yb, wob, (float*)d_out);
}

// Round 5
// 272.920 us; speedup vs baseline: 1.2330x; 1.0470x over previous
//
#include <hip/hip_runtime.h>
#include <stdint.h>

typedef unsigned short u16;
typedef __bf16 bf16x8 __attribute__((ext_vector_type(8)));
typedef float  f32x4  __attribute__((ext_vector_type(4)));

#define B_  2
#define T_  1024
#define C_  2048
#define H_  16
#define D_  128
#define NTENS 4194304   // elements in x and in each W (2*1024*2048 == 2048*2048)

__device__ __forceinline__ u16 f2bf(float f) {
    union { float f; uint32_t u; } v; v.f = f;
    uint32_t r = (v.u + 0x7FFFu + ((v.u >> 16) & 1u)) >> 16;
    return (u16)r;
}
__device__ __forceinline__ float bf2f(u16 h) {
    union { uint32_t u; float f; } v; v.u = ((uint32_t)h) << 16;
    return v.f;
}

// ---------------------------------------------------------------------------
// fp32 -> bf16 conversion: z selects {x, Wq, Wk, Wv, Wo}; dst is contiguous.
// ---------------------------------------------------------------------------
__global__ __launch_bounds__(256) void k_convert(
    const float* __restrict__ x, const float* __restrict__ wq,
    const float* __restrict__ wk, const float* __restrict__ wv,
    const float* __restrict__ wo, u16* __restrict__ dst)
{
    int z = blockIdx.z;
    const float* src = (z == 0) ? x : (z == 1) ? wq : (z == 2) ? wk : (z == 3) ? wv : wo;
    u16* d = dst + (size_t)z * NTENS;
    size_t i = ((size_t)blockIdx.x * 256 + threadIdx.x) * 4;
    float4 v = *(const float4*)(src + i);
    ushort4 o;
    o.x = f2bf(v.x); o.y = f2bf(v.y); o.z = f2bf(v.z); o.w = f2bf(v.w);
    *(ushort4*)(d + i) = o;
}

// ---------------------------------------------------------------------------
// RoPE cos/sin table: [T][64] fp32 (only 65K distinct angles; computing them
// once kills 2M redundant sincosf in k_rope).
// ---------------------------------------------------------------------------
__global__ void k_rope_table(float* __restrict__ ct, float* __restrict__ st)
{
    int t = blockIdx.x, d = threadIdx.x;              // 1024 x 64
    float inv = expf(-(float)d * (9.210340371976184f / 64.0f)); // 10000^(-d/64)
    float th = (float)t * inv;
    float s, c;
    sincosf(th, &s, &c);
    ct[t * 64 + d] = c;
    st[t * 64 + d] = s;
}

// ---------------------------------------------------------------------------
// RoPE in-place on q,k (bto layout). Folds 1/sqrt(D) into q.
// ---------------------------------------------------------------------------
__global__ __launch_bounds__(256) void k_rope(
    u16* __restrict__ q, u16* __restrict__ k,
    const float* __restrict__ ct, const float* __restrict__ st)
{
    int idx = blockIdx.x * 256 + threadIdx.x;  // b:1 | t:10 | h:4 | d:6
    int d = idx & 63;
    int h = (idx >> 6) & 15;
    int t = (idx >> 10) & 1023;
    int b = idx >> 20;
    size_t base = ((size_t)(b * T_ + t)) * C_ + h * D_ + d;
    float c = ct[t * 64 + d], s = st[t * 64 + d];
    const float sc = 0.08838834764831845f;     // 1/sqrt(128)
    float q0 = bf2f(q[base]), q1 = bf2f(q[base + 64]);
    q[base]      = f2bf((q0 * c - q1 * s) * sc);
    q[base + 64] = f2bf((q1 * c + q0 * s) * sc);
    float k0 = bf2f(k[base]), k1 = bf2f(k[base + 64]);
    k[base]      = f2bf(k0 * c - k1 * s);
    k[base + 64] = f2bf(k1 * c + k0 * s);
}

// ---------------------------------------------------------------------------
// NT-form 64x128 MFMA tile GEMM with async global->LDS staging.
//   A: [m][k] row-major, B: [n][k] row-major, D = A*B^T.
// Smaller M-tile than R2/R3 (64 vs 128) -> 2x the blocks -> more resident
// blocks per CU to overlap the per-K-iter vmcnt(0)+barrier drain (the m97
// structural stall). LDS 24 KB/block. XOR-swizzled, zero bank conflicts.
// Waves: 1x4 (each wave = 64 rows x 32 cols, acc 4x2).
// ---------------------------------------------------------------------------
template<typename OutT>
__device__ __forceinline__ void gemm_tile_nt(
    const u16* __restrict__ A, int lda,
    const u16* __restrict__ Bp, int ldb,
    OutT* __restrict__ Cp, int ldc,
    int m0, int n0, int K, float scale,
    u16* As, u16* Bs)
{
    const int tid  = threadIdx.x;
    const int wave = tid >> 6;
    const int lane = tid & 63;
    const int wc   = wave << 5;          // wave col offset 0/32/64/96
    const int frow = lane & 15;
    const int quad = lane >> 4;

    const int lrow8  = lane >> 3;
    const int slot   = lane & 7;
    const int gchunk = slot ^ lrow8;

    f32x4 acc[4][2] = {};

    size_t aoff[2], boff[4];
#pragma unroll
    for (int i = 0; i < 2; ++i) {
        int r = (i << 5) + (wave << 3) + lrow8;          // 0..63
        aoff[i] = (size_t)(m0 + r) * lda + (gchunk << 3);
    }
#pragma unroll
    for (int i = 0; i < 4; ++i) {
        int r = (i << 5) + (wave << 3) + lrow8;          // 0..127
        boff[i] = (size_t)(n0 + r) * ldb + (gchunk << 3);
    }

    for (int kt = 0; kt < K; kt += 64) {
#pragma unroll
        for (int i = 0; i < 2; ++i) {
            int c = (i << 2) + wave;                      // A chunks 0..7
            __builtin_amdgcn_global_load_lds(
                (const __attribute__((address_space(1))) void*)(A + aoff[i] + kt),
                (__attribute__((address_space(3))) void*)(As + (c << 9)), 16, 0, 0);
        }
#pragma unroll
        for (int i = 0; i < 4; ++i) {
            int c = (i << 2) + wave;                      // B chunks 0..15
            __builtin_amdgcn_global_load_lds(
                (const __attribute__((address_space(1))) void*)(Bp + boff[i] + kt),
                (__attribute__((address_space(3))) void*)(Bs + (c << 9)), 16, 0, 0);
        }
        __syncthreads();

#pragma unroll
        for (int ks = 0; ks < 2; ++ks) {
            int lk = (ks << 2) + quad;
            bf16x8 af[4], bfv[2];
#pragma unroll
            for (int i = 0; i < 4; ++i) {
                int ar = (i << 4) + frow;                 // 0..63
                af[i] = *(const bf16x8*)&As[ar * 64 + ((lk ^ (frow & 7)) << 3)];
            }
#pragma unroll
            for (int j = 0; j < 2; ++j) {
                int br = wc + (j << 4) + frow;            // 0..127
                bfv[j] = *(const bf16x8*)&Bs[br * 64 + ((lk ^ (frow & 7)) << 3)];
            }
#pragma unroll
            for (int i = 0; i < 4; ++i)
#pragma unroll
                for (int j = 0; j < 2; ++j)
                    acc[i][j] = __builtin_amdgcn_mfma_f32_16x16x32_bf16(
                        af[i], bfv[j], acc[i][j], 0, 0, 0);
        }
        __syncthreads();
    }

    // epilogue: C/D layout col=lane&15, row=quad*4+reg
#pragma unroll
    for (int i = 0; i < 4; ++i)
#pragma unroll
        for (int j = 0; j < 2; ++j)
#pragma unroll
            for (int r = 0; r < 4; ++r) {
                int m = m0 + (i << 4) + (quad << 2) + r;
                int n = n0 + wc + (j << 4) + frow;
                float val = acc[i][j][r] * scale;
                if constexpr (sizeof(OutT) == 2)
                    Cp[(size_t)m * ldc + n] = f2bf(val);
                else
                    Cp[(size_t)m * ldc + n] = val;
            }
}

// ---------------------------------------------------------------------------
// QKV projection: z selects W and destination. out = x @ W^T, bf16 out (bto).
// Grid (16, 32, 3) = 1536 blocks = 6/CU.
// ---------------------------------------------------------------------------
__global__ __launch_bounds__(256) void k_gemm_qkv(
    const u16* __restrict__ xb, const u16* __restrict__ wq,
    const u16* __restrict__ wk, const u16* __restrict__ wv,
    u16* __restrict__ q, u16* __restrict__ k, u16* __restrict__ v)
{
    __shared__ u16 As[64 * 64], Bs[128 * 64];
    int z = blockIdx.z;
    const u16* Bp = (z == 0) ? wq : (z == 1) ? wk : wv;
    u16* Op       = (z == 0) ? q  : (z == 1) ? k  : v;
    gemm_tile_nt<u16>(xb, C_, Bp, C_, Op, C_,
                      blockIdx.y * 64, blockIdx.x * 128, C_, 1.0f, As, Bs);
}

// ---------------------------------------------------------------------------
// Fused flash attention: S = qK^T (q pre-scaled), online softmax, Y = P V.
// V is staged from [b,t,h,d] via VGPR transpose into stride-72 LDS (kills
// the standalone transpose kernel + vt traffic).
// Grid: 512 blocks = 16 q-tiles(64) x 32 bh, heavy q-tiles first (LPT).
// LDS 50 KB: Qs 64x128, Ks 64x128 (reused as P), Vs 128x72(d-major).
// ---------------------------------------------------------------------------
__global__ __launch_bounds__(256) void k_flash(
    const u16* __restrict__ qb, const u16* __restrict__ kb,
    const u16* __restrict__ vb, u16* __restrict__ yb)
{
    __shared__ u16 Qs[64 * 128];
    __shared__ u16 Ks[64 * 128];   // reused as P after B2
    __shared__ u16 Vs[128 * 72];   // V^T tile: [d][token], stride 72

    const int bx  = blockIdx.x;
    const int bh  = bx & 31, b = bh >> 4, h = bh & 15;
    const int qt  = 15 - (bx >> 5);           // heavy tiles first
    const int tid = threadIdx.x, wave = tid >> 6, lane = tid & 63;
    const int frow = lane & 15, quad = lane >> 4;

    const u16* qbase = qb + (size_t)b * (T_ * C_) + h * D_;
    const u16* kbase = kb + (size_t)b * (T_ * C_) + h * D_;
    const u16* vbase = vb + (size_t)b * (T_ * C_) + h * D_;
    const int q0 = qt << 6;

    // ---- stage Q tile (64 rows x 128 d), XOR-swizzled 16B slots ----
    {
        const int r4 = lane >> 4, s16 = lane & 15;
#pragma unroll
        for (int i = 0; i < 4; ++i) {
            int c = (i << 2) + wave;                 // chunk = 4 rows
            int row = (c << 2) + r4;
            int g = (s16 & 8) | ((s16 & 7) ^ (row & 7));
            __builtin_amdgcn_global_load_lds(
                (const __attribute__((address_space(1))) void*)(qbase + (size_t)(q0 + row) * C_ + (g << 3)),
                (__attribute__((address_space(3))) void*)(Qs + (c << 9)), 16, 0, 0);
        }
    }

    f32x4 Y[8] = {};
    float mrow[4], lrow[4];
#pragma unroll
    for (int r = 0; r < 4; ++r) { mrow[r] = -3e38f; lrow[r] = 0.f; }

    const int tok = q0 + wave * 16 + quad * 4;       // + r = global row

    for (int kt = 0; kt <= qt; ++kt) {
        const int k0 = kt << 6;
        // ---- stage K tile (64x128) via global_load_lds ----
        {
            const int r4 = lane >> 4, s16 = lane & 15;
#pragma unroll
            for (int i = 0; i < 4; ++i) {
                int c = (i << 2) + wave;
                int row = (c << 2) + r4;
                int g = (s16 & 8) | ((s16 & 7) ^ (row & 7));
                __builtin_amdgcn_global_load_lds(
                    (const __attribute__((address_space(1))) void*)(kbase + (size_t)(k0 + row) * C_ + (g << 3)),
                    (__attribute__((address_space(3))) void*)(Ks + (c << 9)), 16, 0, 0);
            }
        }
        // ---- stage V tile (64 tok x 128 d) transposed via VGPR ----
        {
#pragma unroll
            for (int i = 0; i < 4; ++i) {
                int idx = (i << 8) + tid;            // 0..1023 uint4 chunks
                int kr = idx & 63;                   // token within tile
                int n8 = (idx >> 6) << 3;            // d chunk
                uint4 vv = *(const uint4*)&vbase[(size_t)(k0 + kr) * C_ + n8];
                u16 tmp[8];
                *(uint4*)tmp = vv;
#pragma unroll
                for (int e = 0; e < 8; ++e)
                    Vs[(n8 + e) * 72 + kr] = tmp[e];
            }
        }
        __syncthreads();   // B1: tiles staged (covers Q on first iter)

        // ---- S = q K^T  (wave-tile 16 x 64) ----
        f32x4 S[4] = {};
#pragma unroll
        for (int ks = 0; ks < 4; ++ks) {
            int lk = (ks << 2) + quad;
            int sw = ((lk & 8) | ((lk & 7) ^ (frow & 7))) << 3;
            bf16x8 a = *(const bf16x8*)&Qs[(wave * 16 + frow) * 128 + sw];
#pragma unroll
            for (int jj = 0; jj < 4; ++jj) {
                bf16x8 bb = *(const bf16x8*)&Ks[((jj << 4) + frow) * 128 + sw];
                S[jj] = __builtin_amdgcn_mfma_f32_16x16x32_bf16(a, bb, S[jj], 0, 0, 0);
            }
        }

        // ---- causal mask (diagonal tile only) ----
        if (kt == qt) {
#pragma unroll
            for (int jj = 0; jj < 4; ++jj) {
                int colg = k0 + (jj << 4) + frow;
#pragma unroll
                for (int r = 0; r < 4; ++r)
                    if (colg > tok + r) S[jj][r] = -1e30f;
            }
        }

        // ---- online softmax (rows live in 16-lane frow groups) ----
        float al[4];
#pragma unroll
        for (int r = 0; r < 4; ++r) {
            float tm = fmaxf(fmaxf(S[0][r], S[1][r]), fmaxf(S[2][r], S[3][r]));
#pragma unroll
            for (int off = 8; off > 0; off >>= 1) tm = fmaxf(tm, __shfl_xor(tm, off));
            float mn = fmaxf(mrow[r], tm);
            al[r] = __expf(mrow[r] - mn);
            mrow[r] = mn;
            float rs = 0.f;
#pragma unroll
            for (int jj = 0; jj < 4; ++jj) {
                float e = __expf(S[jj][r] - mn);
                S[jj][r] = e;
                rs += e;
            }
#pragma unroll
            for (int off = 8; off > 0; off >>= 1) rs += __shfl_xor(rs, off);
            lrow[r] = lrow[r] * al[r] + rs;
        }
#pragma unroll
        for (int dj = 0; dj < 8; ++dj)
#pragma unroll
            for (int r = 0; r < 4; ++r) Y[dj][r] *= al[r];

        __syncthreads();   // B2: all waves done reading Ks -> safe to overwrite

        // ---- write P into Ks region (A-layout, stride 72, wave-local rows) ----
        u16* Ps = Ks;
#pragma unroll
        for (int jj = 0; jj < 4; ++jj)
#pragma unroll
            for (int r = 0; r < 4; ++r)
                Ps[(wave * 16 + quad * 4 + r) * 72 + (jj << 4) + frow] = f2bf(S[jj][r]);

        // ---- Y += P V  (Vs is [d][token] stride 72) ----
#pragma unroll
        for (int ks = 0; ks < 2; ++ks) {
            bf16x8 pa = *(const bf16x8*)&Ps[(wave * 16 + frow) * 72 + (ks << 5) + (quad << 3)];
#pragma unroll
            for (int dj = 0; dj < 8; ++dj) {
                bf16x8 vv = *(const bf16x8*)&Vs[((dj << 4) + frow) * 72 + (ks << 5) + (quad << 3)];
                Y[dj] = __builtin_amdgcn_mfma_f32_16x16x32_bf16(pa, vv, Y[dj], 0, 0, 0);
            }
        }
        __syncthreads();   // B3: PV reads done before next-iter staging
    }

    // ---- epilogue: Y /= l, store to yb [b,t,h,d] ----
    u16* ybase = yb + (size_t)b * (T_ * C_) + h * D_;
#pragma unroll
    for (int r = 0; r < 4; ++r) {
        float inv = 1.0f / lrow[r];
#pragma unroll
        for (int dj = 0; dj < 8; ++dj)
            ybase[(size_t)(tok + r) * C_ + (dj << 4) + frow] = f2bf(Y[dj][r] * inv);
    }
}

// ---------------------------------------------------------------------------
// out = y @ Wo^T, fp32 output. Grid (16, 32) = 512 blocks = 2/CU (was 1/CU).
// ---------------------------------------------------------------------------
__global__ __launch_bounds__(256) void k_gemm_out(
    const u16* __restrict__ yb, const u16* __restrict__ wo, float* __restrict__ out)
{
    __shared__ u16 As[64 * 64], Bs[128 * 64];
    gemm_tile_nt<float>(yb, C_, wo, C_, out, C_,
                        blockIdx.y * 64, blockIdx.x * 128, C_, 1.0f, As, Bs);
}

// ---------------------------------------------------------------------------
extern "C" void kernel_launch(void* const* d_in, const int* in_sizes, int n_in,
                              void* d_out, int out_size, void* d_ws, size_t ws_size,
                              hipStream_t stream)
{
    (void)in_sizes; (void)n_in; (void)out_size; (void)ws_size;
    const float* x  = (const float*)d_in[0];
    const float* Wq = (const float*)d_in[1];
    const float* Wk = (const float*)d_in[2];
    const float* Wv = (const float*)d_in[3];
    const float* Wo = (const float*)d_in[4];

    u16* ws  = (u16*)d_ws;
    u16* xb  = ws;
    u16* wqb = ws + (size_t)1 * NTENS;
    u16* wkb = ws + (size_t)2 * NTENS;
    u16* wvb = ws + (size_t)3 * NTENS;
    u16* wob = ws + (size_t)4 * NTENS;
    u16* qb  = ws + (size_t)5 * NTENS;
    u16* kb  = ws + (size_t)6 * NTENS;
    u16* vb  = ws + (size_t)7 * NTENS;
    u16* yb  = ws + (size_t)8 * NTENS;
    float* ct = (float*)(ws + (size_t)9 * NTENS);
    float* st = ct + 65536;

    k_convert   <<<dim3(4096, 1, 5), 256, 0, stream>>>(x, Wq, Wk, Wv, Wo, ws);
    k_rope_table<<<dim3(1024), 64, 0, stream>>>(ct, st);
    k_gemm_qkv  <<<dim3(16, 32, 3), 256, 0, stream>>>(xb, wqb, wkb, wvb, qb, kb, vb);
    k_rope      <<<dim3(8192), 256, 0, stream>>>(qb, kb, ct, st);
    k_flash     <<<dim3(512), 256, 0, stream>>>(qb, kb, vb, yb);
    k_gemm_out  <<<dim3(16, 32, 1), 256, 0, stream>>>(yb, wob, (float*)d_out);
}

// Round 6
// 271.264 us; speedup vs baseline: 1.2405x; 1.0061x over previous
//
#include <hip/hip_runtime.h>
#include <stdint.h>

typedef unsigned short u16;
typedef __bf16 bf16x8 __attribute__((ext_vector_type(8)));
typedef float  f32x4  __attribute__((ext_vector_type(4)));

#define B_  2
#define T_  1024
#define C_  2048
#define H_  16
#define D_  128
#define NTENS 4194304   // elements in x and in each W (2*1024*2048 == 2048*2048)

__device__ __forceinline__ u16 f2bf(float f) {
    union { float f; uint32_t u; } v; v.f = f;
    uint32_t r = (v.u + 0x7FFFu + ((v.u >> 16) & 1u)) >> 16;
    return (u16)r;
}
__device__ __forceinline__ float bf2f(u16 h) {
    union { uint32_t u; float f; } v; v.u = ((uint32_t)h) << 16;
    return v.f;
}

// ---------------------------------------------------------------------------
// fp32 -> bf16 conversion: z selects {x, Wq, Wk, Wv, Wo}; dst is contiguous.
// ---------------------------------------------------------------------------
__global__ __launch_bounds__(256) void k_convert(
    const float* __restrict__ x, const float* __restrict__ wq,
    const float* __restrict__ wk, const float* __restrict__ wv,
    const float* __restrict__ wo, u16* __restrict__ dst)
{
    int z = blockIdx.z;
    const float* src = (z == 0) ? x : (z == 1) ? wq : (z == 2) ? wk : (z == 3) ? wv : wo;
    u16* d = dst + (size_t)z * NTENS;
    size_t i = ((size_t)blockIdx.x * 256 + threadIdx.x) * 4;
    float4 v = *(const float4*)(src + i);
    ushort4 o;
    o.x = f2bf(v.x); o.y = f2bf(v.y); o.z = f2bf(v.z); o.w = f2bf(v.w);
    *(ushort4*)(d + i) = o;
}

// ---------------------------------------------------------------------------
// RoPE cos/sin table: [T][64] fp32 (65K distinct angles, computed once).
// Consumed by the qkv epilogue.
// ---------------------------------------------------------------------------
__global__ void k_rope_table(float* __restrict__ ct, float* __restrict__ st)
{
    int t = blockIdx.x, d = threadIdx.x;              // 1024 x 64
    float inv = expf(-(float)d * (9.210340371976184f / 64.0f)); // 10000^(-d/64)
    float th = (float)t * inv;
    float s, c;
    sincosf(th, &s, &c);
    ct[t * 64 + d] = c;
    st[t * 64 + d] = s;
}

// ---------------------------------------------------------------------------
// NT-form MTILE x 128 MFMA tile GEMM with async global->LDS staging.
//   A: [m][k] row-major, B: [n][k] row-major, D = A*B^T.
// XOR-swizzled LDS (zero bank conflicts, verified R2). Waves 1x4.
// EPI: 0 = fp32 store, 1 = bf16 store, 2 = RoPE epilogue (qkv; n-tile==head;
//      z==2 falls back to plain bf16 store; z==0 also applies 1/sqrt(D)).
// ---------------------------------------------------------------------------
template<int MTILE, int EPI>
__device__ __forceinline__ void gemm_tile_nt(
    const u16* __restrict__ A, int lda,
    const u16* __restrict__ Bp, int ldb,
    void* __restrict__ Cp, int ldc,
    int m0, int n0, int K,
    u16* SMEM, const float* __restrict__ ct, const float* __restrict__ st, int z)
{
    constexpr int MF  = MTILE / 16;      // m-frags per wave
    constexpr int ACH = MTILE / 32;      // A-chunk loop count
    u16* As = SMEM;                      // MTILE x 64
    u16* Bs = SMEM + MTILE * 64;         // 128 x 64

    const int tid  = threadIdx.x;
    const int wave = tid >> 6;
    const int lane = tid & 63;
    const int wc   = wave << 5;          // wave col offset 0/32/64/96
    const int frow = lane & 15;
    const int quad = lane >> 4;

    const int lrow8  = lane >> 3;
    const int slot   = lane & 7;
    const int gchunk = slot ^ lrow8;

    f32x4 acc[MF][2] = {};

    size_t aoff[ACH], boff[4];
#pragma unroll
    for (int i = 0; i < ACH; ++i) {
        int c = (i << 2) + wave;
        int r = (c << 3) + lrow8;                        // 0..MTILE-1
        aoff[i] = (size_t)(m0 + r) * lda + (gchunk << 3);
    }
#pragma unroll
    for (int i = 0; i < 4; ++i) {
        int r = (i << 5) + (wave << 3) + lrow8;          // 0..127
        boff[i] = (size_t)(n0 + r) * ldb + (gchunk << 3);
    }

    for (int kt = 0; kt < K; kt += 64) {
#pragma unroll
        for (int i = 0; i < ACH; ++i) {
            int c = (i << 2) + wave;
            __builtin_amdgcn_global_load_lds(
                (const __attribute__((address_space(1))) void*)(A + aoff[i] + kt),
                (__attribute__((address_space(3))) void*)(As + (c << 9)), 16, 0, 0);
        }
#pragma unroll
        for (int i = 0; i < 4; ++i) {
            int c = (i << 2) + wave;
            __builtin_amdgcn_global_load_lds(
                (const __attribute__((address_space(1))) void*)(Bp + boff[i] + kt),
                (__attribute__((address_space(3))) void*)(Bs + (c << 9)), 16, 0, 0);
        }
        __syncthreads();

#pragma unroll
        for (int ks = 0; ks < 2; ++ks) {
            int lk = (ks << 2) + quad;
            bf16x8 af[MF], bfv[2];
#pragma unroll
            for (int i = 0; i < MF; ++i) {
                int ar = (i << 4) + frow;
                af[i] = *(const bf16x8*)&As[ar * 64 + ((lk ^ (frow & 7)) << 3)];
            }
#pragma unroll
            for (int j = 0; j < 2; ++j) {
                int br = wc + (j << 4) + frow;
                bfv[j] = *(const bf16x8*)&Bs[br * 64 + ((lk ^ (frow & 7)) << 3)];
            }
#pragma unroll
            for (int i = 0; i < MF; ++i)
#pragma unroll
                for (int j = 0; j < 2; ++j)
                    acc[i][j] = __builtin_amdgcn_mfma_f32_16x16x32_bf16(
                        af[i], bfv[j], acc[i][j], 0, 0, 0);
        }
        __syncthreads();
    }

    if constexpr (EPI == 2) {
        if (z < 2) {
            // ---- RoPE epilogue: exchange (d, d+64) pairs via LDS ----
            // L is 64 x 136 u16 (8704 <= 12288 SMEM); stride 136 keeps 16B
            // alignment and spreads banks (rl*68%32 = rl*4 pattern).
            u16* L = SMEM;
#pragma unroll
            for (int i = 0; i < MF; ++i)
#pragma unroll
                for (int j = 0; j < 2; ++j)
#pragma unroll
                    for (int r = 0; r < 4; ++r) {
                        int rl = (i << 4) + (quad << 2) + r;
                        int d  = wc + (j << 4) + frow;
                        L[rl * 136 + d] = f2bf(acc[i][j][r]);
                    }
            __syncthreads();

            int rl = tid >> 2;                  // 0..63
            int d0 = (tid & 3) << 4;            // 0/16/32/48
            int t  = (m0 + rl) & 1023;
            uint4 lo4[2], hi4[2];
            lo4[0] = *(const uint4*)&L[rl * 136 + d0];
            lo4[1] = *(const uint4*)&L[rl * 136 + d0 + 8];
            hi4[0] = *(const uint4*)&L[rl * 136 + 64 + d0];
            hi4[1] = *(const uint4*)&L[rl * 136 + 64 + d0 + 8];
            const u16* lo = (const u16*)lo4;
            const u16* hi = (const u16*)hi4;
            float sc = (z == 0) ? 0.08838834764831845f : 1.0f;
            u16 o0[16], o1[16];
            const float* ctp = ct + t * 64 + d0;
            const float* stp = st + t * 64 + d0;
#pragma unroll
            for (int e = 0; e < 16; ++e) {
                float c = ctp[e], s = stp[e];
                float a = bf2f(lo[e]), b = bf2f(hi[e]);
                o0[e] = f2bf((a * c - b * s) * sc);
                o1[e] = f2bf((b * c + a * s) * sc);
            }
            u16* Op = (u16*)Cp;
            size_t rbase = (size_t)(m0 + rl) * ldc + n0;
            *(uint4*)&Op[rbase + d0]          = ((uint4*)o0)[0];
            *(uint4*)&Op[rbase + d0 + 8]      = ((uint4*)o0)[1];
            *(uint4*)&Op[rbase + 64 + d0]     = ((uint4*)o1)[0];
            *(uint4*)&Op[rbase + 64 + d0 + 8] = ((uint4*)o1)[1];
            return;
        }
        // z == 2 (v): plain bf16 store
        u16* Op = (u16*)Cp;
#pragma unroll
        for (int i = 0; i < MF; ++i)
#pragma unroll
            for (int j = 0; j < 2; ++j)
#pragma unroll
                for (int r = 0; r < 4; ++r) {
                    int m = m0 + (i << 4) + (quad << 2) + r;
                    int n = n0 + wc + (j << 4) + frow;
                    Op[(size_t)m * ldc + n] = f2bf(acc[i][j][r]);
                }
        return;
    }

    // EPI 0/1: plain store. C/D layout col=lane&15, row=quad*4+reg.
#pragma unroll
    for (int i = 0; i < MF; ++i)
#pragma unroll
        for (int j = 0; j < 2; ++j)
#pragma unroll
            for (int r = 0; r < 4; ++r) {
                int m = m0 + (i << 4) + (quad << 2) + r;
                int n = n0 + wc + (j << 4) + frow;
                if constexpr (EPI == 1)
                    ((u16*)Cp)[(size_t)m * ldc + n] = f2bf(acc[i][j][r]);
                else
                    ((float*)Cp)[(size_t)m * ldc + n] = acc[i][j][r];
            }
}

// ---------------------------------------------------------------------------
// QKV projection with fused RoPE epilogue. Grid (16, 32, 3) = 6 blocks/CU.
// n-tile (128) == one head, so (d, d+64) rotate pairs are in-block.
// ---------------------------------------------------------------------------
__global__ __launch_bounds__(256) void k_gemm_qkv(
    const u16* __restrict__ xb, const u16* __restrict__ wq,
    const u16* __restrict__ wk, const u16* __restrict__ wv,
    u16* __restrict__ q, u16* __restrict__ k, u16* __restrict__ v,
    const float* __restrict__ ct, const float* __restrict__ st)
{
    __shared__ u16 SMEM[64 * 64 + 128 * 64];
    int z = blockIdx.z;
    const u16* Bp = (z == 0) ? wq : (z == 1) ? wk : wv;
    u16* Op       = (z == 0) ? q  : (z == 1) ? k  : v;
    gemm_tile_nt<64, 2>(xb, C_, Bp, C_, Op, C_,
                        blockIdx.y * 64, blockIdx.x * 128, C_, SMEM, ct, st, z);
}

// ---------------------------------------------------------------------------
// Fused flash attention: S = qK^T (q pre-scaled), online softmax, Y = P V.
// V staged from [b,t,h,d] via VGPR transpose into stride-72 LDS.
// Grid: 512 blocks; LPT pairing: first 256 blocks qt=15..8, second 256
// qt=0..7, so each CU's two blocks sum to 15 k-iterations.
// LDS 50 KB: Qs 64x128, Ks 64x128 (reused as P), Vs 128x72 (d-major).
// ---------------------------------------------------------------------------
__global__ __launch_bounds__(256) void k_flash(
    const u16* __restrict__ qb, const u16* __restrict__ kb,
    const u16* __restrict__ vb, u16* __restrict__ yb)
{
    __shared__ u16 Qs[64 * 128];
    __shared__ u16 Ks[64 * 128];   // reused as P after B2
    __shared__ u16 Vs[128 * 72];   // V^T tile: [d][token], stride 72

    const int bx  = blockIdx.x;
    const int bh  = bx & 31, b = bh >> 4, h = bh & 15;
    const int qt  = (bx < 256) ? (15 - (bx >> 5)) : ((bx >> 5) - 8);
    const int tid = threadIdx.x, wave = tid >> 6, lane = tid & 63;
    const int frow = lane & 15, quad = lane >> 4;

    const u16* qbase = qb + (size_t)b * (T_ * C_) + h * D_;
    const u16* kbase = kb + (size_t)b * (T_ * C_) + h * D_;
    const u16* vbase = vb + (size_t)b * (T_ * C_) + h * D_;
    const int q0 = qt << 6;

    // ---- stage Q tile (64 rows x 128 d), XOR-swizzled 16B slots ----
    {
        const int r4 = lane >> 4, s16 = lane & 15;
#pragma unroll
        for (int i = 0; i < 4; ++i) {
            int c = (i << 2) + wave;                 // chunk = 4 rows
            int row = (c << 2) + r4;
            int g = (s16 & 8) | ((s16 & 7) ^ (row & 7));
            __builtin_amdgcn_global_load_lds(
                (const __attribute__((address_space(1))) void*)(qbase + (size_t)(q0 + row) * C_ + (g << 3)),
                (__attribute__((address_space(3))) void*)(Qs + (c << 9)), 16, 0, 0);
        }
    }

    f32x4 Y[8] = {};
    float mrow[4], lrow[4];
#pragma unroll
    for (int r = 0; r < 4; ++r) { mrow[r] = -3e38f; lrow[r] = 0.f; }

    const int tok = q0 + wave * 16 + quad * 4;       // + r = global row

    for (int kt = 0; kt <= qt; ++kt) {
        const int k0 = kt << 6;
        // ---- stage K tile (64x128) via global_load_lds ----
        {
            const int r4 = lane >> 4, s16 = lane & 15;
#pragma unroll
            for (int i = 0; i < 4; ++i) {
                int c = (i << 2) + wave;
                int row = (c << 2) + r4;
                int g = (s16 & 8) | ((s16 & 7) ^ (row & 7));
                __builtin_amdgcn_global_load_lds(
                    (const __attribute__((address_space(1))) void*)(kbase + (size_t)(k0 + row) * C_ + (g << 3)),
                    (__attribute__((address_space(3))) void*)(Ks + (c << 9)), 16, 0, 0);
            }
        }
        // ---- stage V tile (64 tok x 128 d) transposed via VGPR ----
        {
#pragma unroll
            for (int i = 0; i < 4; ++i) {
                int idx = (i << 8) + tid;            // 0..1023 uint4 chunks
                int kr = idx & 63;                   // token within tile
                int n8 = (idx >> 6) << 3;            // d chunk
                uint4 vv = *(const uint4*)&vbase[(size_t)(k0 + kr) * C_ + n8];
                u16 tmp[8];
                *(uint4*)tmp = vv;
#pragma unroll
                for (int e = 0; e < 8; ++e)
                    Vs[(n8 + e) * 72 + kr] = tmp[e];
            }
        }
        __syncthreads();   // B1: tiles staged (covers Q on first iter)

        // ---- S = q K^T  (wave-tile 16 x 64) ----
        f32x4 S[4] = {};
#pragma unroll
        for (int ks = 0; ks < 4; ++ks) {
            int lk = (ks << 2) + quad;
            int sw = ((lk & 8) | ((lk & 7) ^ (frow & 7))) << 3;
            bf16x8 a = *(const bf16x8*)&Qs[(wave * 16 + frow) * 128 + sw];
#pragma unroll
            for (int jj = 0; jj < 4; ++jj) {
                bf16x8 bb = *(const bf16x8*)&Ks[((jj << 4) + frow) * 128 + sw];
                S[jj] = __builtin_amdgcn_mfma_f32_16x16x32_bf16(a, bb, S[jj], 0, 0, 0);
            }
        }

        // ---- causal mask (diagonal tile only) ----
        if (kt == qt) {
#pragma unroll
            for (int jj = 0; jj < 4; ++jj) {
                int colg = k0 + (jj << 4) + frow;
#pragma unroll
                for (int r = 0; r < 4; ++r)
                    if (colg > tok + r) S[jj][r] = -1e30f;
            }
        }

        // ---- online softmax (rows live in 16-lane frow groups) ----
        float al[4];
#pragma unroll
        for (int r = 0; r < 4; ++r) {
            float tm = fmaxf(fmaxf(S[0][r], S[1][r]), fmaxf(S[2][r], S[3][r]));
#pragma unroll
            for (int off = 8; off > 0; off >>= 1) tm = fmaxf(tm, __shfl_xor(tm, off));
            float mn = fmaxf(mrow[r], tm);
            al[r] = __expf(mrow[r] - mn);
            mrow[r] = mn;
            float rs = 0.f;
#pragma unroll
            for (int jj = 0; jj < 4; ++jj) {
                float e = __expf(S[jj][r] - mn);
                S[jj][r] = e;
                rs += e;
            }
#pragma unroll
            for (int off = 8; off > 0; off >>= 1) rs += __shfl_xor(rs, off);
            lrow[r] = lrow[r] * al[r] + rs;
        }
#pragma unroll
        for (int dj = 0; dj < 8; ++dj)
#pragma unroll
            for (int r = 0; r < 4; ++r) Y[dj][r] *= al[r];

        __syncthreads();   // B2: all waves done reading Ks -> safe to overwrite

        // ---- write P into Ks region (A-layout, stride 72, wave-local rows) ----
        u16* Ps = Ks;
#pragma unroll
        for (int jj = 0; jj < 4; ++jj)
#pragma unroll
            for (int r = 0; r < 4; ++r)
                Ps[(wave * 16 + quad * 4 + r) * 72 + (jj << 4) + frow] = f2bf(S[jj][r]);

        // ---- Y += P V  (Vs is [d][token] stride 72) ----
#pragma unroll
        for (int ks = 0; ks < 2; ++ks) {
            bf16x8 pa = *(const bf16x8*)&Ps[(wave * 16 + frow) * 72 + (ks << 5) + (quad << 3)];
#pragma unroll
            for (int dj = 0; dj < 8; ++dj) {
                bf16x8 vv = *(const bf16x8*)&Vs[((dj << 4) + frow) * 72 + (ks << 5) + (quad << 3)];
                Y[dj] = __builtin_amdgcn_mfma_f32_16x16x32_bf16(pa, vv, Y[dj], 0, 0, 0);
            }
        }
        __syncthreads();   // B3: PV reads done before next-iter staging
    }

    // ---- epilogue: Y /= l, store to yb [b,t,h,d] ----
    u16* ybase = yb + (size_t)b * (T_ * C_) + h * D_;
#pragma unroll
    for (int r = 0; r < 4; ++r) {
        float inv = 1.0f / lrow[r];
#pragma unroll
        for (int dj = 0; dj < 8; ++dj)
            ybase[(size_t)(tok + r) * C_ + (dj << 4) + frow] = f2bf(Y[dj][r] * inv);
    }
}

// ---------------------------------------------------------------------------
// out = y @ Wo^T, fp32 output. 32x128 tile, grid (16,64) = 1024 blocks =
// 4/CU (was 2/CU) — oversubscription for the K=2048 drain-bound loop.
// ---------------------------------------------------------------------------
__global__ __launch_bounds__(256) void k_gemm_out(
    const u16* __restrict__ yb, const u16* __restrict__ wo, float* __restrict__ out)
{
    __shared__ u16 SMEM[32 * 64 + 128 * 64];
    gemm_tile_nt<32, 0>(yb, C_, wo, C_, out, C_,
                        blockIdx.y * 32, blockIdx.x * 128, C_, SMEM, nullptr, nullptr, 0);
}

// ---------------------------------------------------------------------------
extern "C" void kernel_launch(void* const* d_in, const int* in_sizes, int n_in,
                              void* d_out, int out_size, void* d_ws, size_t ws_size,
                              hipStream_t stream)
{
    (void)in_sizes; (void)n_in; (void)out_size; (void)ws_size;
    const float* x  = (const float*)d_in[0];
    const float* Wq = (const float*)d_in[1];
    const float* Wk = (const float*)d_in[2];
    const float* Wv = (const float*)d_in[3];
    const float* Wo = (const float*)d_in[4];

    u16* ws  = (u16*)d_ws;
    u16* xb  = ws;
    u16* wqb = ws + (size_t)1 * NTENS;
    u16* wkb = ws + (size_t)2 * NTENS;
    u16* wvb = ws + (size_t)3 * NTENS;
    u16* wob = ws + (size_t)4 * NTENS;
    u16* qb  = ws + (size_t)5 * NTENS;
    u16* kb  = ws + (size_t)6 * NTENS;
    u16* vb  = ws + (size_t)7 * NTENS;
    u16* yb  = ws + (size_t)8 * NTENS;
    float* ct = (float*)(ws + (size_t)9 * NTENS);
    float* st = ct + 65536;

    k_convert   <<<dim3(4096, 1, 5), 256, 0, stream>>>(x, Wq, Wk, Wv, Wo, ws);
    k_rope_table<<<dim3(1024), 64, 0, stream>>>(ct, st);
    k_gemm_qkv  <<<dim3(16, 32, 3), 256, 0, stream>>>(xb, wqb, wkb, wvb, qb, kb, vb, ct, st);
    k_flash     <<<dim3(512), 256, 0, stream>>>(qb, kb, vb, yb);
    k_gemm_out  <<<dim3(16, 64, 1), 256, 0, stream>>>(yb, wob, (float*)d_out);
}

// Round 7
// 262.894 us; speedup vs baseline: 1.2800x; 1.0318x over previous
//
#include <hip/hip_runtime.h>
#include <stdint.h>

typedef unsigned short u16;
typedef __bf16 bf16x8 __attribute__((ext_vector_type(8)));
typedef float  f32x4  __attribute__((ext_vector_type(4)));

#define B_  2
#define T_  1024
#define C_  2048
#define H_  16
#define D_  128
#define NTENS 4194304   // elements in x and in each W (2*1024*2048 == 2048*2048)

__device__ __forceinline__ u16 f2bf(float f) {
    union { float f; uint32_t u; } v; v.f = f;
    uint32_t r = (v.u + 0x7FFFu + ((v.u >> 16) & 1u)) >> 16;
    return (u16)r;
}
__device__ __forceinline__ float bf2f(u16 h) {
    union { uint32_t u; float f; } v; v.u = ((uint32_t)h) << 16;
    return v.f;
}

// ---------------------------------------------------------------------------
// fp32 -> bf16 conversion: z selects {x, Wq, Wk, Wv, Wo}; dst is contiguous.
// ---------------------------------------------------------------------------
__global__ __launch_bounds__(256) void k_convert(
    const float* __restrict__ x, const float* __restrict__ wq,
    const float* __restrict__ wk, const float* __restrict__ wv,
    const float* __restrict__ wo, u16* __restrict__ dst)
{
    int z = blockIdx.z;
    const float* src = (z == 0) ? x : (z == 1) ? wq : (z == 2) ? wk : (z == 3) ? wv : wo;
    u16* d = dst + (size_t)z * NTENS;
    size_t i = ((size_t)blockIdx.x * 256 + threadIdx.x) * 4;
    float4 v = *(const float4*)(src + i);
    ushort4 o;
    o.x = f2bf(v.x); o.y = f2bf(v.y); o.z = f2bf(v.z); o.w = f2bf(v.w);
    *(ushort4*)(d + i) = o;
}

// ---------------------------------------------------------------------------
// RoPE cos/sin table: [T][64] fp32 (65K distinct angles, computed once).
// ---------------------------------------------------------------------------
__global__ void k_rope_table(float* __restrict__ ct, float* __restrict__ st)
{
    int t = blockIdx.x, d = threadIdx.x;              // 1024 x 64
    float inv = expf(-(float)d * (9.210340371976184f / 64.0f)); // 10000^(-d/64)
    float th = (float)t * inv;
    float s, c;
    sincosf(th, &s, &c);
    ct[t * 64 + d] = c;
    st[t * 64 + d] = s;
}

// ---------------------------------------------------------------------------
// NT-form MTILE x 128 MFMA tile GEMM with async global->LDS staging.
//   A: [m][k] row-major, B: [n][k] row-major, D = A*B^T.
// XOR-swizzled LDS (zero bank conflicts). Waves 1x4.
// Wave->column map: wave w owns cols {16w..16w+15} (j=0) and {64+16w..} (j=1)
// so the RoPE pair (d, d+64) sits in one lane's two j-accumulators.
// EPI: 0 = fp32 store, 1 = bf16 store, 2 = RoPE epilogue (z<2) in registers.
// ---------------------------------------------------------------------------
template<int MTILE, int EPI>
__device__ __forceinline__ void gemm_tile_nt(
    const u16* __restrict__ A, int lda,
    const u16* __restrict__ Bp, int ldb,
    void* __restrict__ Cp, int ldc,
    int m0, int n0, int K,
    u16* SMEM, const float* __restrict__ ct, const float* __restrict__ st, int z)
{
    constexpr int MF  = MTILE / 16;      // m-frags per wave
    constexpr int ACH = MTILE / 32;      // A-chunk loop count
    u16* As = SMEM;                      // MTILE x 64
    u16* Bs = SMEM + MTILE * 64;         // 128 x 64

    const int tid  = threadIdx.x;
    const int wave = tid >> 6;
    const int lane = tid & 63;
    const int frow = lane & 15;
    const int quad = lane >> 4;

    const int lrow8  = lane >> 3;
    const int slot   = lane & 7;
    const int gchunk = slot ^ lrow8;

    f32x4 acc[MF][2] = {};

    size_t aoff[ACH], boff[4];
#pragma unroll
    for (int i = 0; i < ACH; ++i) {
        int c = (i << 2) + wave;
        int r = (c << 3) + lrow8;                        // 0..MTILE-1
        aoff[i] = (size_t)(m0 + r) * lda + (gchunk << 3);
    }
#pragma unroll
    for (int i = 0; i < 4; ++i) {
        int r = (i << 5) + (wave << 3) + lrow8;          // 0..127
        boff[i] = (size_t)(n0 + r) * ldb + (gchunk << 3);
    }

    for (int kt = 0; kt < K; kt += 64) {
#pragma unroll
        for (int i = 0; i < ACH; ++i) {
            int c = (i << 2) + wave;
            __builtin_amdgcn_global_load_lds(
                (const __attribute__((address_space(1))) void*)(A + aoff[i] + kt),
                (__attribute__((address_space(3))) void*)(As + (c << 9)), 16, 0, 0);
        }
#pragma unroll
        for (int i = 0; i < 4; ++i) {
            int c = (i << 2) + wave;
            __builtin_amdgcn_global_load_lds(
                (const __attribute__((address_space(1))) void*)(Bp + boff[i] + kt),
                (__attribute__((address_space(3))) void*)(Bs + (c << 9)), 16, 0, 0);
        }
        __syncthreads();

#pragma unroll
        for (int ks = 0; ks < 2; ++ks) {
            int lk = (ks << 2) + quad;
            bf16x8 af[MF], bfv[2];
#pragma unroll
            for (int i = 0; i < MF; ++i) {
                int ar = (i << 4) + frow;
                af[i] = *(const bf16x8*)&As[ar * 64 + ((lk ^ (frow & 7)) << 3)];
            }
#pragma unroll
            for (int j = 0; j < 2; ++j) {
                int br = (wave << 4) + (j << 6) + frow;  // cols 16w / 64+16w
                bfv[j] = *(const bf16x8*)&Bs[br * 64 + ((lk ^ (frow & 7)) << 3)];
            }
#pragma unroll
            for (int i = 0; i < MF; ++i)
#pragma unroll
                for (int j = 0; j < 2; ++j)
                    acc[i][j] = __builtin_amdgcn_mfma_f32_16x16x32_bf16(
                        af[i], bfv[j], acc[i][j], 0, 0, 0);
        }
        __syncthreads();
    }

    if constexpr (EPI == 2) {
        if (z < 2) {
            // RoPE in registers: d = 16*wave+frow in [0,64); pair = j0/j1.
            const int d = (wave << 4) + frow;
            const float sc = (z == 0) ? 0.08838834764831845f : 1.0f;
            u16* Op = (u16*)Cp;
#pragma unroll
            for (int i = 0; i < MF; ++i)
#pragma unroll
                for (int r = 0; r < 4; ++r) {
                    int m = m0 + (i << 4) + (quad << 2) + r;
                    int t = m & 1023;
                    float c = ct[t * 64 + d], s = st[t * 64 + d];
                    float a = acc[i][0][r], bb = acc[i][1][r];
                    Op[(size_t)m * ldc + n0 + d]      = f2bf((a * c - bb * s) * sc);
                    Op[(size_t)m * ldc + n0 + d + 64] = f2bf((bb * c + a * s) * sc);
                }
            return;
        }
    }

    // plain store (EPI 0/1, and EPI 2 with z==2).
#pragma unroll
    for (int i = 0; i < MF; ++i)
#pragma unroll
        for (int j = 0; j < 2; ++j)
#pragma unroll
            for (int r = 0; r < 4; ++r) {
                int m = m0 + (i << 4) + (quad << 2) + r;
                int n = n0 + (wave << 4) + (j << 6) + frow;
                if constexpr (EPI == 0)
                    ((float*)Cp)[(size_t)m * ldc + n] = acc[i][j][r];
                else
                    ((u16*)Cp)[(size_t)m * ldc + n] = f2bf(acc[i][j][r]);
            }
}

// ---------------------------------------------------------------------------
// QKV projection with in-register RoPE epilogue. Grid (16,32,3) = 6 blk/CU.
// ---------------------------------------------------------------------------
__global__ __launch_bounds__(256) void k_gemm_qkv(
    const u16* __restrict__ xb, const u16* __restrict__ wq,
    const u16* __restrict__ wk, const u16* __restrict__ wv,
    u16* __restrict__ q, u16* __restrict__ k, u16* __restrict__ v,
    const float* __restrict__ ct, const float* __restrict__ st)
{
    __shared__ u16 SMEM[64 * 64 + 128 * 64];
    int z = blockIdx.z;
    const u16* Bp = (z == 0) ? wq : (z == 1) ? wk : wv;
    u16* Op       = (z == 0) ? q  : (z == 1) ? k  : v;
    gemm_tile_nt<64, 2>(xb, C_, Bp, C_, Op, C_,
                        blockIdx.y * 64, blockIdx.x * 128, C_, SMEM, ct, st, z);
}

// ---------------------------------------------------------------------------
// Fused flash attention v2: KV-tile 128 (half the iterations of v1).
// Q-tile 64 rows; Q fragments live in registers. LDS = Ks[128x128] (K tile,
// reused as P after QK) + Vs[128x128] (V^T, staged via VGPR transpose),
// both XOR-swizzled at 16B granularity with 3-bit key (bank-clean).
// Grid 512, LPT pairing: qt=15..8 then qt=0..7 (each CU pair sums to 9 iters).
// ---------------------------------------------------------------------------
__global__ __launch_bounds__(256) void k_flash(
    const u16* __restrict__ qb, const u16* __restrict__ kb,
    const u16* __restrict__ vb, u16* __restrict__ yb)
{
    __shared__ u16 Ks[128 * 128];   // [tok][d]; P (stride 136) reuses this
    __shared__ u16 Vs[128 * 128];   // [d][tok]

    const int bx  = blockIdx.x;
    const int bh  = bx & 31, b = bh >> 4, h = bh & 15;
    const int qt  = (bx < 256) ? (15 - (bx >> 5)) : ((bx >> 5) - 8);
    const int KT  = (qt >> 1) + 1;
    const int tid = threadIdx.x, wave = tid >> 6, lane = tid & 63;
    const int frow = lane & 15, quad = lane >> 4;

    const u16* qbase = qb + (size_t)b * (T_ * C_) + h * D_;
    const u16* kbase = kb + (size_t)b * (T_ * C_) + h * D_;
    const u16* vbase = vb + (size_t)b * (T_ * C_) + h * D_;
    const int q0 = qt << 6;

    // ---- Q fragments in registers (wave w owns q-rows q0+16w..+15) ----
    bf16x8 qf[4];
#pragma unroll
    for (int ks = 0; ks < 4; ++ks)
        qf[ks] = *(const bf16x8*)&qbase[(size_t)(q0 + (wave << 4) + frow) * C_
                                        + (ks << 5) + (quad << 3)];

    f32x4 Y[8] = {};
    float mrow[4], lrow[4];
#pragma unroll
    for (int r = 0; r < 4; ++r) { mrow[r] = -3e38f; lrow[r] = 0.f; }

    const int tok = q0 + (wave << 4) + (quad << 2);  // + r = global q row

    for (int kt = 0; kt < KT; ++kt) {
        const int k0 = kt << 7;
        // ---- stage K tile (128 tok x 128 d) via global_load_lds ----
        {
            const int r4 = lane >> 4, s16 = lane & 15;
#pragma unroll
            for (int i = 0; i < 8; ++i) {
                int c = (i << 2) + wave;             // 0..31, 4 rows each
                int row = (c << 2) + r4;             // 0..127
                int g = (s16 & 8) | ((s16 & 7) ^ (row & 7));
                __builtin_amdgcn_global_load_lds(
                    (const __attribute__((address_space(1))) void*)(kbase + (size_t)(k0 + row) * C_ + (g << 3)),
                    (__attribute__((address_space(3))) void*)(Ks + (c << 9)), 16, 0, 0);
            }
        }
        // ---- stage V^T tile via VGPR transpose (scatter is bank-clean) ----
        {
#pragma unroll
            for (int i = 0; i < 8; ++i) {
                int idx = (i << 8) + tid;            // 0..2047 uint4 chunks
                int kr  = idx & 127;                 // token
                int n8  = (idx >> 7) << 3;           // d base 0..120
                uint4 vv = *(const uint4*)&vbase[(size_t)(k0 + kr) * C_ + n8];
                u16 tmp[8];
                *(uint4*)tmp = vv;
                int s = kr >> 3, t7 = kr & 7;
#pragma unroll
                for (int e = 0; e < 8; ++e) {
                    int d = n8 + e;
                    int swz = (s & 8) | ((s & 7) ^ (d & 7));
                    Vs[d * 128 + (swz << 3) + t7] = tmp[e];
                }
            }
        }
        __syncthreads();   // B1: tiles staged

        // ---- S = q K^T  (wave-tile 16 x 128) ----
        f32x4 S[8] = {};
#pragma unroll
        for (int ks = 0; ks < 4; ++ks) {
            int lk = (ks << 2) + quad;
            int sw = ((lk & 8) | ((lk & 7) ^ (frow & 7))) << 3;
#pragma unroll
            for (int jj = 0; jj < 8; ++jj) {
                bf16x8 bb = *(const bf16x8*)&Ks[((jj << 4) + frow) * 128 + sw];
                S[jj] = __builtin_amdgcn_mfma_f32_16x16x32_bf16(qf[ks], bb, S[jj], 0, 0, 0);
            }
        }

        // ---- causal mask (only the last kv-tile intersects the diagonal) ----
        if (kt == KT - 1) {
#pragma unroll
            for (int jj = 0; jj < 8; ++jj) {
                int colg = k0 + (jj << 4) + frow;
#pragma unroll
                for (int r = 0; r < 4; ++r)
                    if (colg > tok + r) S[jj][r] = -1e30f;
            }
        }

        // ---- online softmax (rows live in 16-lane frow groups) ----
        float al[4];
#pragma unroll
        for (int r = 0; r < 4; ++r) {
            float tm = -3e38f;
#pragma unroll
            for (int jj = 0; jj < 8; ++jj) tm = fmaxf(tm, S[jj][r]);
#pragma unroll
            for (int off = 8; off > 0; off >>= 1) tm = fmaxf(tm, __shfl_xor(tm, off));
            float mn = fmaxf(mrow[r], tm);
            al[r] = __expf(mrow[r] - mn);
            mrow[r] = mn;
            float rs = 0.f;
#pragma unroll
            for (int jj = 0; jj < 8; ++jj) {
                float e = __expf(S[jj][r] - mn);
                S[jj][r] = e;
                rs += e;
            }
#pragma unroll
            for (int off = 8; off > 0; off >>= 1) rs += __shfl_xor(rs, off);
            lrow[r] = lrow[r] * al[r] + rs;
        }
#pragma unroll
        for (int dj = 0; dj < 8; ++dj)
#pragma unroll
            for (int r = 0; r < 4; ++r) Y[dj][r] *= al[r];

        __syncthreads();   // B2: Ks reads done -> safe to overwrite with P

        // ---- write P into Ks region (A-layout, stride 136) ----
        u16* Ps = Ks;
#pragma unroll
        for (int jj = 0; jj < 8; ++jj)
#pragma unroll
            for (int r = 0; r < 4; ++r)
                Ps[((wave << 4) + (quad << 2) + r) * 136 + (jj << 4) + frow] = f2bf(S[jj][r]);

        // ---- Y += P V ----
#pragma unroll
        for (int ks = 0; ks < 4; ++ks) {
            bf16x8 pa = *(const bf16x8*)&Ps[((wave << 4) + frow) * 136 + (ks << 5) + (quad << 3)];
            int lk = (ks << 2) + quad;
            int sw = ((lk & 8) | ((lk & 7) ^ (frow & 7))) << 3;
#pragma unroll
            for (int dj = 0; dj < 8; ++dj) {
                bf16x8 vv = *(const bf16x8*)&Vs[((dj << 4) + frow) * 128 + sw];
                Y[dj] = __builtin_amdgcn_mfma_f32_16x16x32_bf16(pa, vv, Y[dj], 0, 0, 0);
            }
        }
        __syncthreads();   // B3: PV reads done before next-iter staging
    }

    // ---- epilogue: Y /= l, store to yb [b,t,h,d] ----
    u16* ybase = yb + (size_t)b * (T_ * C_) + h * D_;
#pragma unroll
    for (int r = 0; r < 4; ++r) {
        float inv = 1.0f / lrow[r];
#pragma unroll
        for (int dj = 0; dj < 8; ++dj)
            ybase[(size_t)(tok + r) * C_ + (dj << 4) + frow] = f2bf(Y[dj][r] * inv);
    }
}

// ---------------------------------------------------------------------------
// out = y @ Wo^T, fp32 output. 64x128 tile, grid (16,32) = 512 blocks = 2/CU.
// ---------------------------------------------------------------------------
__global__ __launch_bounds__(256) void k_gemm_out(
    const u16* __restrict__ yb, const u16* __restrict__ wo, float* __restrict__ out)
{
    __shared__ u16 SMEM[64 * 64 + 128 * 64];
    gemm_tile_nt<64, 0>(yb, C_, wo, C_, out, C_,
                        blockIdx.y * 64, blockIdx.x * 128, C_, SMEM, nullptr, nullptr, 0);
}

// ---------------------------------------------------------------------------
extern "C" void kernel_launch(void* const* d_in, const int* in_sizes, int n_in,
                              void* d_out, int out_size, void* d_ws, size_t ws_size,
                              hipStream_t stream)
{
    (void)in_sizes; (void)n_in; (void)out_size; (void)ws_size;
    const float* x  = (const float*)d_in[0];
    const float* Wq = (const float*)d_in[1];
    const float* Wk = (const float*)d_in[2];
    const float* Wv = (const float*)d_in[3];
    const float* Wo = (const float*)d_in[4];

    u16* ws  = (u16*)d_ws;
    u16* xb  = ws;
    u16* wqb = ws + (size_t)1 * NTENS;
    u16* wkb = ws + (size_t)2 * NTENS;
    u16* wvb = ws + (size_t)3 * NTENS;
    u16* wob = ws + (size_t)4 * NTENS;
    u16* qb  = ws + (size_t)5 * NTENS;
    u16* kb  = ws + (size_t)6 * NTENS;
    u16* vb  = ws + (size_t)7 * NTENS;
    u16* yb  = ws + (size_t)8 * NTENS;
    float* ct = (float*)(ws + (size_t)9 * NTENS);
    float* st = ct + 65536;

    k_convert   <<<dim3(4096, 1, 5), 256, 0, stream>>>(x, Wq, Wk, Wv, Wo, ws);
    k_rope_table<<<dim3(1024), 64, 0, stream>>>(ct, st);
    k_gemm_qkv  <<<dim3(16, 32, 3), 256, 0, stream>>>(xb, wqb, wkb, wvb, qb, kb, vb, ct, st);
    k_flash     <<<dim3(512), 256, 0, stream>>>(qb, kb, vb, yb);
    k_gemm_out  <<<dim3(16, 32, 1), 256, 0, stream>>>(yb, wob, (float*)d_out);
}

// Round 8
// 259.944 us; speedup vs baseline: 1.2945x; 1.0113x over previous
//
#include <hip/hip_runtime.h>
#include <stdint.h>

typedef unsigned short u16;
typedef __bf16 bf16x8 __attribute__((ext_vector_type(8)));
typedef float  f32x4  __attribute__((ext_vector_type(4)));

#define B_  2
#define T_  1024
#define C_  2048
#define H_  16
#define D_  128
#define NTENS 4194304   // elements in x and in each W (2*1024*2048 == 2048*2048)

__device__ __forceinline__ u16 f2bf(float f) {
    union { float f; uint32_t u; } v; v.f = f;
    uint32_t r = (v.u + 0x7FFFu + ((v.u >> 16) & 1u)) >> 16;
    return (u16)r;
}
__device__ __forceinline__ float bf2f(u16 h) {
    union { uint32_t u; float f; } v; v.u = ((uint32_t)h) << 16;
    return v.f;
}

// ---------------------------------------------------------------------------
// fp32 -> bf16 conversion; z in [0,5): {x,Wq,Wk,Wv,Wo}. z==5: RoPE table
// (first 64 blocks only) — folded here to save a launch.
// ---------------------------------------------------------------------------
__global__ __launch_bounds__(256) void k_convert(
    const float* __restrict__ x, const float* __restrict__ wq,
    const float* __restrict__ wk, const float* __restrict__ wv,
    const float* __restrict__ wo, u16* __restrict__ dst,
    float* __restrict__ ct, float* __restrict__ st)
{
    int z = blockIdx.z;
    if (z == 5) {
        int idx = blockIdx.x * 256 + threadIdx.x;
        if (idx < 65536) {
            int t = idx >> 6, d = idx & 63;
            float inv = expf(-(float)d * (9.210340371976184f / 64.0f));
            float th = (float)t * inv;
            float s, c;
            sincosf(th, &s, &c);
            ct[idx] = c;
            st[idx] = s;
        }
        return;
    }
    const float* src = (z == 0) ? x : (z == 1) ? wq : (z == 2) ? wk : (z == 3) ? wv : wo;
    u16* d = dst + (size_t)z * NTENS;
    size_t i = ((size_t)blockIdx.x * 256 + threadIdx.x) * 4;
    float4 v = *(const float4*)(src + i);
    ushort4 o;
    o.x = f2bf(v.x); o.y = f2bf(v.y); o.z = f2bf(v.z); o.w = f2bf(v.w);
    *(ushort4*)(d + i) = o;
}

// ---------------------------------------------------------------------------
// One-shot V transpose: vb [b,t,h,d] -> vt [bh][d][t]. Each unique tile
// transposed ONCE here (flash v2 re-transposed each ~9x in-block).
// ---------------------------------------------------------------------------
__global__ __launch_bounds__(256) void k_transpose_v(
    const u16* __restrict__ vb, u16* __restrict__ vt)
{
    __shared__ u16 L[64 * 136];
    int t0 = blockIdx.x << 6;                  // 16 t-tiles of 64
    int bh = blockIdx.y, b = bh >> 4, h = bh & 15;
    const u16* src = vb + (size_t)b * (T_ * C_) + h * D_;
    u16* dst = vt + (size_t)bh * (D_ * T_);
    int tid = threadIdx.x;
#pragma unroll
    for (int i = 0; i < 4; ++i) {
        int idx = (i << 8) + tid;              // 0..1023 uint4 chunks
        int r = idx >> 4, s = idx & 15;
        *(uint4*)&L[r * 136 + (s << 3)] =
            *(const uint4*)&src[(size_t)(t0 + r) * C_ + (s << 3)];
    }
    __syncthreads();
#pragma unroll
    for (int i = 0; i < 8; ++i) {
        int idx = (i << 8) + tid;              // 0..2047 groups of 4 t
        int d = idx >> 4, s = idx & 15;
        int t = s << 2;
        ushort4 o;
        o.x = L[(t    ) * 136 + d];
        o.y = L[(t + 1) * 136 + d];
        o.z = L[(t + 2) * 136 + d];
        o.w = L[(t + 3) * 136 + d];
        *(ushort4*)&dst[(size_t)d * T_ + t0 + t] = o;
    }
}

// ---------------------------------------------------------------------------
// NT-form MTILE x 128 MFMA tile GEMM with async global->LDS staging.
// XOR-swizzled LDS (zero bank conflicts). Waves 1x4; wave w owns cols
// {16w..16w+15} and {64+16w..+15} so the RoPE pair (d,d+64) is in-lane.
// EPI: 0 = fp32 store, 1 = bf16 store, 2 = RoPE epilogue (z<2) in registers.
// ---------------------------------------------------------------------------
template<int MTILE, int EPI>
__device__ __forceinline__ void gemm_tile_nt(
    const u16* __restrict__ A, int lda,
    const u16* __restrict__ Bp, int ldb,
    void* __restrict__ Cp, int ldc,
    int m0, int n0, int K,
    u16* SMEM, const float* __restrict__ ct, const float* __restrict__ st, int z)
{
    constexpr int MF  = MTILE / 16;
    constexpr int ACH = MTILE / 32;
    u16* As = SMEM;
    u16* Bs = SMEM + MTILE * 64;

    const int tid  = threadIdx.x;
    const int wave = tid >> 6;
    const int lane = tid & 63;
    const int frow = lane & 15;
    const int quad = lane >> 4;

    const int lrow8  = lane >> 3;
    const int slot   = lane & 7;
    const int gchunk = slot ^ lrow8;

    f32x4 acc[MF][2] = {};

    size_t aoff[ACH], boff[4];
#pragma unroll
    for (int i = 0; i < ACH; ++i) {
        int c = (i << 2) + wave;
        int r = (c << 3) + lrow8;
        aoff[i] = (size_t)(m0 + r) * lda + (gchunk << 3);
    }
#pragma unroll
    for (int i = 0; i < 4; ++i) {
        int r = (i << 5) + (wave << 3) + lrow8;
        boff[i] = (size_t)(n0 + r) * ldb + (gchunk << 3);
    }

    for (int kt = 0; kt < K; kt += 64) {
#pragma unroll
        for (int i = 0; i < ACH; ++i) {
            int c = (i << 2) + wave;
            __builtin_amdgcn_global_load_lds(
                (const __attribute__((address_space(1))) void*)(A + aoff[i] + kt),
                (__attribute__((address_space(3))) void*)(As + (c << 9)), 16, 0, 0);
        }
#pragma unroll
        for (int i = 0; i < 4; ++i) {
            int c = (i << 2) + wave;
            __builtin_amdgcn_global_load_lds(
                (const __attribute__((address_space(1))) void*)(Bp + boff[i] + kt),
                (__attribute__((address_space(3))) void*)(Bs + (c << 9)), 16, 0, 0);
        }
        __syncthreads();

#pragma unroll
        for (int ks = 0; ks < 2; ++ks) {
            int lk = (ks << 2) + quad;
            bf16x8 af[MF], bfv[2];
#pragma unroll
            for (int i = 0; i < MF; ++i) {
                int ar = (i << 4) + frow;
                af[i] = *(const bf16x8*)&As[ar * 64 + ((lk ^ (frow & 7)) << 3)];
            }
#pragma unroll
            for (int j = 0; j < 2; ++j) {
                int br = (wave << 4) + (j << 6) + frow;
                bfv[j] = *(const bf16x8*)&Bs[br * 64 + ((lk ^ (frow & 7)) << 3)];
            }
#pragma unroll
            for (int i = 0; i < MF; ++i)
#pragma unroll
                for (int j = 0; j < 2; ++j)
                    acc[i][j] = __builtin_amdgcn_mfma_f32_16x16x32_bf16(
                        af[i], bfv[j], acc[i][j], 0, 0, 0);
        }
        __syncthreads();
    }

    if constexpr (EPI == 2) {
        if (z < 2) {
            const int d = (wave << 4) + frow;
            const float sc = (z == 0) ? 0.08838834764831845f : 1.0f;
            u16* Op = (u16*)Cp;
#pragma unroll
            for (int i = 0; i < MF; ++i)
#pragma unroll
                for (int r = 0; r < 4; ++r) {
                    int m = m0 + (i << 4) + (quad << 2) + r;
                    int t = m & 1023;
                    float c = ct[t * 64 + d], s = st[t * 64 + d];
                    float a = acc[i][0][r], bb = acc[i][1][r];
                    Op[(size_t)m * ldc + n0 + d]      = f2bf((a * c - bb * s) * sc);
                    Op[(size_t)m * ldc + n0 + d + 64] = f2bf((bb * c + a * s) * sc);
                }
            return;
        }
    }

#pragma unroll
    for (int i = 0; i < MF; ++i)
#pragma unroll
        for (int j = 0; j < 2; ++j)
#pragma unroll
            for (int r = 0; r < 4; ++r) {
                int m = m0 + (i << 4) + (quad << 2) + r;
                int n = n0 + (wave << 4) + (j << 6) + frow;
                if constexpr (EPI == 0)
                    ((float*)Cp)[(size_t)m * ldc + n] = acc[i][j][r];
                else
                    ((u16*)Cp)[(size_t)m * ldc + n] = f2bf(acc[i][j][r]);
            }
}

// ---------------------------------------------------------------------------
// QKV projection with in-register RoPE epilogue. Grid (16,32,3) = 6 blk/CU.
// ---------------------------------------------------------------------------
__global__ __launch_bounds__(256) void k_gemm_qkv(
    const u16* __restrict__ xb, const u16* __restrict__ wq,
    const u16* __restrict__ wk, const u16* __restrict__ wv,
    u16* __restrict__ q, u16* __restrict__ k, u16* __restrict__ v,
    const float* __restrict__ ct, const float* __restrict__ st)
{
    __shared__ u16 SMEM[64 * 64 + 128 * 64];
    int z = blockIdx.z;
    const u16* Bp = (z == 0) ? wq : (z == 1) ? wk : wv;
    u16* Op       = (z == 0) ? q  : (z == 1) ? k  : v;
    gemm_tile_nt<64, 2>(xb, C_, Bp, C_, Op, C_,
                        blockIdx.y * 64, blockIdx.x * 128, C_, SMEM, ct, st, z);
}

// ---------------------------------------------------------------------------
// Fused flash attention v3: KV-tile 128, Q in registers, BOTH K and V^T
// staged with global_load_lds (V pre-transposed by k_transpose_v — no more
// per-iteration scalar LDS transpose). Grid 512, LPT pairing (pairs sum 9).
// LDS 64 KB: Ks[128x128] (reused as P, stride 136), Vs[128x128] ([d][tok]).
// ---------------------------------------------------------------------------
__global__ __launch_bounds__(256) void k_flash(
    const u16* __restrict__ qb, const u16* __restrict__ kb,
    const u16* __restrict__ vt, u16* __restrict__ yb)
{
    __shared__ u16 Ks[128 * 128];   // [tok][d]; P (stride 136) reuses this
    __shared__ u16 Vs[128 * 128];   // [d][tok]

    const int bx  = blockIdx.x;
    const int bh  = bx & 31, b = bh >> 4, h = bh & 15;
    const int qt  = (bx < 256) ? (15 - (bx >> 5)) : ((bx >> 5) - 8);
    const int KT  = (qt >> 1) + 1;
    const int tid = threadIdx.x, wave = tid >> 6, lane = tid & 63;
    const int frow = lane & 15, quad = lane >> 4;

    const u16* qbase = qb + (size_t)b * (T_ * C_) + h * D_;
    const u16* kbase = kb + (size_t)b * (T_ * C_) + h * D_;
    const u16* vbase = vt + (size_t)bh * (D_ * T_);
    const int q0 = qt << 6;

    // ---- Q fragments in registers (wave w owns q-rows q0+16w..+15) ----
    bf16x8 qf[4];
#pragma unroll
    for (int ks = 0; ks < 4; ++ks)
        qf[ks] = *(const bf16x8*)&qbase[(size_t)(q0 + (wave << 4) + frow) * C_
                                        + (ks << 5) + (quad << 3)];

    f32x4 Y[8] = {};
    float mrow[4], lrow[4];
#pragma unroll
    for (int r = 0; r < 4; ++r) { mrow[r] = -3e38f; lrow[r] = 0.f; }

    const int tok = q0 + (wave << 4) + (quad << 2);  // + r = global q row

    for (int kt = 0; kt < KT; ++kt) {
        const int k0 = kt << 7;
        // ---- stage K tile (128 tok x 128 d) and V^T tile (128 d x 128 tok) ----
        {
            const int r4 = lane >> 4, s16 = lane & 15;
#pragma unroll
            for (int i = 0; i < 8; ++i) {
                int c = (i << 2) + wave;             // 0..31, 4 rows each
                int row = (c << 2) + r4;             // 0..127
                int g = (s16 & 8) | ((s16 & 7) ^ (row & 7));
                __builtin_amdgcn_global_load_lds(
                    (const __attribute__((address_space(1))) void*)(kbase + (size_t)(k0 + row) * C_ + (g << 3)),
                    (__attribute__((address_space(3))) void*)(Ks + (c << 9)), 16, 0, 0);
                __builtin_amdgcn_global_load_lds(
                    (const __attribute__((address_space(1))) void*)(vbase + (size_t)row * T_ + k0 + (g << 3)),
                    (__attribute__((address_space(3))) void*)(Vs + (c << 9)), 16, 0, 0);
            }
        }
        __syncthreads();   // B1: tiles staged

        // ---- S = q K^T  (wave-tile 16 x 128) ----
        f32x4 S[8] = {};
#pragma unroll
        for (int ks = 0; ks < 4; ++ks) {
            int lk = (ks << 2) + quad;
            int sw = ((lk & 8) | ((lk & 7) ^ (frow & 7))) << 3;
#pragma unroll
            for (int jj = 0; jj < 8; ++jj) {
                bf16x8 bb = *(const bf16x8*)&Ks[((jj << 4) + frow) * 128 + sw];
                S[jj] = __builtin_amdgcn_mfma_f32_16x16x32_bf16(qf[ks], bb, S[jj], 0, 0, 0);
            }
        }

        // ---- causal mask (only the last kv-tile intersects the diagonal) ----
        if (kt == KT - 1) {
#pragma unroll
            for (int jj = 0; jj < 8; ++jj) {
                int colg = k0 + (jj << 4) + frow;
#pragma unroll
                for (int r = 0; r < 4; ++r)
                    if (colg > tok + r) S[jj][r] = -1e30f;
            }
        }

        // ---- online softmax (rows live in 16-lane frow groups) ----
        float al[4];
#pragma unroll
        for (int r = 0; r < 4; ++r) {
            float tm = -3e38f;
#pragma unroll
            for (int jj = 0; jj < 8; ++jj) tm = fmaxf(tm, S[jj][r]);
#pragma unroll
            for (int off = 8; off > 0; off >>= 1) tm = fmaxf(tm, __shfl_xor(tm, off));
            float mn = fmaxf(mrow[r], tm);
            al[r] = __expf(mrow[r] - mn);
            mrow[r] = mn;
            float rs = 0.f;
#pragma unroll
            for (int jj = 0; jj < 8; ++jj) {
                float e = __expf(S[jj][r] - mn);
                S[jj][r] = e;
                rs += e;
            }
#pragma unroll
            for (int off = 8; off > 0; off >>= 1) rs += __shfl_xor(rs, off);
            lrow[r] = lrow[r] * al[r] + rs;
        }
#pragma unroll
        for (int dj = 0; dj < 8; ++dj)
#pragma unroll
            for (int r = 0; r < 4; ++r) Y[dj][r] *= al[r];

        __syncthreads();   // B2: Ks reads done -> safe to overwrite with P

        // ---- write P into Ks region (A-layout, stride 136) ----
        u16* Ps = Ks;
#pragma unroll
        for (int jj = 0; jj < 8; ++jj)
#pragma unroll
            for (int r = 0; r < 4; ++r)
                Ps[((wave << 4) + (quad << 2) + r) * 136 + (jj << 4) + frow] = f2bf(S[jj][r]);

        // ---- Y += P V ----
#pragma unroll
        for (int ks = 0; ks < 4; ++ks) {
            bf16x8 pa = *(const bf16x8*)&Ps[((wave << 4) + frow) * 136 + (ks << 5) + (quad << 3)];
            int lk = (ks << 2) + quad;
            int sw = ((lk & 8) | ((lk & 7) ^ (frow & 7))) << 3;
#pragma unroll
            for (int dj = 0; dj < 8; ++dj) {
                bf16x8 vv = *(const bf16x8*)&Vs[((dj << 4) + frow) * 128 + sw];
                Y[dj] = __builtin_amdgcn_mfma_f32_16x16x32_bf16(pa, vv, Y[dj], 0, 0, 0);
            }
        }
        __syncthreads();   // B3: PV reads done before next-iter staging
    }

    // ---- epilogue: Y /= l, store to yb [b,t,h,d] ----
    u16* ybase = yb + (size_t)b * (T_ * C_) + h * D_;
#pragma unroll
    for (int r = 0; r < 4; ++r) {
        float inv = 1.0f / lrow[r];
#pragma unroll
        for (int dj = 0; dj < 8; ++dj)
            ybase[(size_t)(tok + r) * C_ + (dj << 4) + frow] = f2bf(Y[dj][r] * inv);
    }
}

// ---------------------------------------------------------------------------
// out = y @ Wo^T, fp32 output. 64x128 tile, grid (16,32) = 512 blocks = 2/CU.
// ---------------------------------------------------------------------------
__global__ __launch_bounds__(256) void k_gemm_out(
    const u16* __restrict__ yb, const u16* __restrict__ wo, float* __restrict__ out)
{
    __shared__ u16 SMEM[64 * 64 + 128 * 64];
    gemm_tile_nt<64, 0>(yb, C_, wo, C_, out, C_,
                        blockIdx.y * 64, blockIdx.x * 128, C_, SMEM, nullptr, nullptr, 0);
}

// ---------------------------------------------------------------------------
extern "C" void kernel_launch(void* const* d_in, const int* in_sizes, int n_in,
                              void* d_out, int out_size, void* d_ws, size_t ws_size,
                              hipStream_t stream)
{
    (void)in_sizes; (void)n_in; (void)out_size; (void)ws_size;
    const float* x  = (const float*)d_in[0];
    const float* Wq = (const float*)d_in[1];
    const float* Wk = (const float*)d_in[2];
    const float* Wv = (const float*)d_in[3];
    const float* Wo = (const float*)d_in[4];

    u16* ws  = (u16*)d_ws;
    u16* xb  = ws;
    u16* wqb = ws + (size_t)1 * NTENS;
    u16* wkb = ws + (size_t)2 * NTENS;
    u16* wvb = ws + (size_t)3 * NTENS;
    u16* wob = ws + (size_t)4 * NTENS;
    u16* qb  = ws + (size_t)5 * NTENS;
    u16* kb  = ws + (size_t)6 * NTENS;
    u16* vb  = ws + (size_t)7 * NTENS;
    u16* yb  = ws + (size_t)8 * NTENS;
    u16* vt  = ws + (size_t)9 * NTENS;         // [bh][d][t]
    float* ct = (float*)(ws + (size_t)10 * NTENS);
    float* st = ct + 65536;

    k_convert    <<<dim3(4096, 1, 6), 256, 0, stream>>>(x, Wq, Wk, Wv, Wo, ws, ct, st);
    k_gemm_qkv   <<<dim3(16, 32, 3), 256, 0, stream>>>(xb, wqb, wkb, wvb, qb, kb, vb, ct, st);
    k_transpose_v<<<dim3(16, 32), 256, 0, stream>>>(vb, vt);
    k_flash      <<<dim3(512), 256, 0, stream>>>(qb, kb, vt, yb);
    k_gemm_out   <<<dim3(16, 32, 1), 256, 0, stream>>>(yb, wob, (float*)d_out);
}